// Round 5
// baseline (739.670 us; speedup 1.0000x reference)
//
#include <hip/hip_runtime.h>
#include <cstdint>
#include <cstddef>

#define B 64
#define PCH 512
#define O_CAPS 32
#define OD 16
#define IDC 8
#define I_CAPS 4096
#define ICHUNK 16
#define NPBLK 256  // I_CAPS / ICHUNK
#define KDIM 4608  // 512*9

typedef __attribute__((ext_vector_type(8))) short bf16x8;
typedef __attribute__((ext_vector_type(4))) float f32x4;
typedef __attribute__((ext_vector_type(8))) unsigned short u16x8;

// workspace layout (in floats)
#define OFF_POSE 0
#define SZ_POSE (B * I_CAPS * IDC)                    // 2,097,152
#define OFF_BLOG (OFF_POSE + SZ_POSE)
#define SZ_BLOG ((size_t)B * I_CAPS * O_CAPS)         // 8,388,608
#define OFF_PART (OFF_BLOG + SZ_BLOG)
#define SZ_PART ((size_t)NPBLK * 4 * 16 * 512)        // 8,388,608
#define OFF_VBUF (OFF_PART + SZ_PART)
#define SZ_V (B * O_CAPS * OD)                        // 32,768
#define OFF_OUTC (OFF_VBUF + SZ_V)
#define OFF_WB (OFF_OUTC + SZ_V)                      // bf16 512*4608
#define OFF_BIAS (OFF_WB + (PCH * KDIM) / 2)
#define OFF_WR (OFF_BIAS + 512)                       // bf16 caps_w, 16.7M elems
#define SZ_WR ((size_t)O_CAPS * I_CAPS * OD * IDC / 2)  // 8,388,608 floats
// Aim (bf16, 9,437,184 float-equiv) aliases blog + head of part: dead before
// routing<0> writes part / routing<1> writes blog.
#define OFF_AIM OFF_BLOG
#define OFF_H OFF_BLOG  // h reuses blog after routing

__device__ inline unsigned short f2bf(float f) {
  union { float f; unsigned int u; } v; v.f = f;
  unsigned int r = v.u + 0x7fff + ((v.u >> 16) & 1);  // RNE
  return (unsigned short)(r >> 16);
}
__device__ inline float bf2f(unsigned short u) {
  union { unsigned int u; float f; } v; v.u = ((unsigned int)u) << 16;
  return v.f;
}

// ---------------------------------------------------------------------------
// prep_wr: caps_w fp32 -> bf16, same layout [o][i][d][k].
// ---------------------------------------------------------------------------
__global__ __launch_bounds__(256) void prep_wr(
    const float* __restrict__ cw, unsigned short* __restrict__ wr) {
  const size_t t = (size_t)blockIdx.x * 256 + threadIdx.x;  // 2,097,152
  const float4* s = (const float4*)cw + t * 2;
  const float4 a = s[0], b = s[1];
  u16x8 v;
  v[0] = f2bf(a.x); v[1] = f2bf(a.y); v[2] = f2bf(a.z); v[3] = f2bf(a.w);
  v[4] = f2bf(b.x); v[5] = f2bf(b.y); v[6] = f2bf(b.z); v[7] = f2bf(b.w);
  ((u16x8*)wr)[t] = v;
}

// ---------------------------------------------------------------------------
// prep_wb: Wb[n][k] = bf16(conv_w[n][k] * inv[n]); bias[n] = beta - mean*inv.
// ---------------------------------------------------------------------------
__global__ __launch_bounds__(256) void prep_wb(
    const float* __restrict__ cw, const float* __restrict__ gamma,
    const float* __restrict__ beta, const float* __restrict__ mean,
    const float* __restrict__ var, unsigned short* __restrict__ wb,
    float* __restrict__ bias) {
  const int n = blockIdx.x;
  const float inv = gamma[n] * rsqrtf(var[n] + 1e-5f);
  if (threadIdx.x == 0) bias[n] = beta[n] - mean[n] * inv;
  for (int k = threadIdx.x; k < KDIM; k += 256)
    wb[(size_t)n * KDIM + k] = f2bf(cw[(size_t)n * KDIM + k] * inv);
}

// ---------------------------------------------------------------------------
// prep_aim: im2col to bf16. Aim[m=(b,px)][k=ci*9+tap]
// ---------------------------------------------------------------------------
__global__ __launch_bounds__(256) void prep_aim(
    const float* __restrict__ x, unsigned short* __restrict__ aim) {
  __shared__ float lxp[32 * 100];
  const int b = blockIdx.x;
  const int ci0 = blockIdx.y * 32;
  const int tid = threadIdx.x;
  for (int t = tid; t < 3200; t += 256) lxp[t] = 0.f;
  __syncthreads();
  for (int t = tid; t < 2048; t += 256) {
    const int ci = t >> 6, px = t & 63;
    lxp[ci * 100 + 11 + (px >> 3) * 10 + (px & 7)] =
        x[((size_t)b * PCH + ci0 + ci) * 64 + px];
  }
  __syncthreads();
  for (int t = tid; t < 4608; t += 256) {
    const int px = t / 72;
    const int kk = (t - px * 72) * 4;
    unsigned short v[4];
#pragma unroll
    for (int j = 0; j < 4; ++j) {
      const int k = kk + j;
      const int ci = k / 9;
      const int tap = k - ci * 9;
      const int kh = tap / 3, kw = tap - kh * 3;
      v[j] = f2bf(lxp[ci * 100 + ((px >> 3) + kh) * 10 + (px & 7) + kw]);
    }
    ushort4* dst =
        (ushort4*)(aim + (size_t)(b * 64 + px) * KDIM + ci0 * 9 + kk);
    *dst = make_ushort4(v[0], v[1], v[2], v[3]);
  }
}

// ---------------------------------------------------------------------------
// conv_gemm (unchanged from round 4): 64x64 tiles, mfma 16x16x32_bf16,
// global_load_lds staging with XOR swizzle, fused bias+ReLU+squash -> pose.
// ---------------------------------------------------------------------------
__global__ __launch_bounds__(256) void conv_gemm(
    const unsigned short* __restrict__ aim, const unsigned short* __restrict__ wb,
    const float* __restrict__ bias, float* __restrict__ pose) {
  __shared__ unsigned short lA[64 * 64];
  __shared__ unsigned short lB[64 * 64];
  const int tid = threadIdx.x;
  const int lane = tid & 63, wv = tid >> 6;
  const int wm = wv & 1, wn = wv >> 1;
  const int n0 = blockIdx.x * 64;
  const int m0 = blockIdx.y * 64;
  const int rsub = lane >> 3, seg = lane & 7;

  f32x4 acc[2][2];
#pragma unroll
  for (int a = 0; a < 2; ++a)
#pragma unroll
    for (int c = 0; c < 2; ++c) acc[a][c] = (f32x4){0.f, 0.f, 0.f, 0.f};

  for (int k0 = 0; k0 < KDIM; k0 += 64) {
    __syncthreads();
#pragma unroll
    for (int it = 0; it < 2; ++it) {
      const int r = it * 32 + wv * 8 + rsub;
      const int c = seg ^ (r & 7);
      const unsigned short* ga = aim + (size_t)(m0 + r) * KDIM + k0 + c * 8;
      __builtin_amdgcn_global_load_lds(
          (const __attribute__((address_space(1))) void*)ga,
          (__attribute__((address_space(3))) void*)(lA + (it * 32 + wv * 8) * 64),
          16, 0, 0);
      const unsigned short* gb = wb + (size_t)(n0 + r) * KDIM + k0 + c * 8;
      __builtin_amdgcn_global_load_lds(
          (const __attribute__((address_space(1))) void*)gb,
          (__attribute__((address_space(3))) void*)(lB + (it * 32 + wv * 8) * 64),
          16, 0, 0);
    }
    __syncthreads();
#pragma unroll
    for (int kc = 0; kc < 2; ++kc) {
      const int g = kc * 4 + (lane >> 4);
      const int ml = wm * 32 + (lane & 15);
      const int nl = wn * 32 + (lane & 15);
      const int sa = (g ^ (ml & 7)) * 8;
      const int sb = (g ^ (nl & 7)) * 8;
      const bf16x8 a0 = *(const bf16x8*)(lA + (ml + 0) * 64 + sa);
      const bf16x8 a1 = *(const bf16x8*)(lA + (ml + 16) * 64 + sa);
      const bf16x8 b0 = *(const bf16x8*)(lB + (nl + 0) * 64 + sb);
      const bf16x8 b1 = *(const bf16x8*)(lB + (nl + 16) * 64 + sb);
      acc[0][0] = __builtin_amdgcn_mfma_f32_16x16x32_bf16(a0, b0, acc[0][0], 0, 0, 0);
      acc[0][1] = __builtin_amdgcn_mfma_f32_16x16x32_bf16(a0, b1, acc[0][1], 0, 0, 0);
      acc[1][0] = __builtin_amdgcn_mfma_f32_16x16x32_bf16(a1, b0, acc[1][0], 0, 0, 0);
      acc[1][1] = __builtin_amdgcn_mfma_f32_16x16x32_bf16(a1, b1, acc[1][1], 0, 0, 0);
    }
  }

  const int bq = blockIdx.y;
  float bsv[2];
#pragma unroll
  for (int ni = 0; ni < 2; ++ni)
    bsv[ni] = bias[n0 + wn * 32 + ni * 16 + (lane & 15)];
#pragma unroll
  for (int mi = 0; mi < 2; ++mi) {
#pragma unroll
    for (int ni = 0; ni < 2; ++ni) {
      const int n = n0 + wn * 32 + ni * 16 + (lane & 15);
#pragma unroll
      for (int reg = 0; reg < 4; ++reg) {
        float v = fmaxf(acc[mi][ni][reg] + bsv[ni], 0.f);
        float s2 = v * v;
        s2 += __shfl_xor(s2, 1, 64);
        s2 += __shfl_xor(s2, 2, 64);
        s2 += __shfl_xor(s2, 4, 64);
        const float sc = s2 / (1.f + s2) / (sqrtf(s2) + 1e-8f);
        const int px = wm * 32 + mi * 16 + (lane >> 4) * 4 + reg;
        pose[((size_t)bq * I_CAPS + (n >> 3) * 64 + px) * IDC + (n & 7)] =
            v * sc;
      }
    }
  }
}

// ---------------------------------------------------------------------------
// Routing phase v4: 256 threads = 4 waves, block = 16 i x 16 b. Wave owns
// 4 b, register acc[4][8]. W staged from bf16 (half traffic), converted to
// fp32 on LDS write (pitch-65 float4 layout, proven conflict-free). Grid
// (256, 4) = 1024 blocks -> 4 blocks/CU, 16 waves/CU.
// ---------------------------------------------------------------------------
template <int MODE>
__global__ __launch_bounds__(256, 4) void routing_phase(
    const float* __restrict__ pose, const unsigned short* __restrict__ wr,
    const float* __restrict__ vbuf, float* __restrict__ blog,
    float* __restrict__ partials) {
  __shared__ float4 lw4[2][16 * 65];  // 2 x 16.6 KB (fp32 expanded)
  const int tid = threadIdx.x;
  const int lane = tid & 63;
  const int wv = tid >> 6;  // 0..3
  const int o = lane >> 1, dh = lane & 1;
  const int i0 = blockIdx.x * ICHUNK;
  const int b0 = blockIdx.y * 16;

  // staging map: thread t covers cols l in {sl, sl+32}, ushort8 sq
  const int sl = tid >> 3;  // 0..31
  const int sq = tid & 7;   // 0..7

  float acc[4][8];
#pragma unroll
  for (int bb = 0; bb < 4; ++bb)
#pragma unroll
    for (int j = 0; j < 8; ++j) acc[bb][j] = 0.f;

  // stage W slice for capsule i into buf (bf16 global -> fp32 LDS)
  auto stage = [&](int i, int buf) {
#pragma unroll
    for (int half = 0; half < 2; ++half) {
      const int l = sl + half * 32;
      // ushort8 index: o*(I_CAPS*16) + i*16 + dh*8 + sq, with o=l>>1, dh=l&1
      const u16x8 v = ((const u16x8*)wr)[(size_t)(l >> 1) * (I_CAPS * 16) +
                                         (size_t)i * 16 + (l & 1) * 8 + sq];
#pragma unroll
      for (int e = 0; e < 2; ++e) {
        float4 f;
        f.x = bf2f(v[e * 4 + 0]);
        f.y = bf2f(v[e * 4 + 1]);
        f.z = bf2f(v[e * 4 + 2]);
        f.w = bf2f(v[e * 4 + 3]);
        lw4[buf][(sq * 2 + e) * 65 + l] = f;
      }
    }
  };

  stage(i0, 0);
  __syncthreads();

  for (int ii = 0; ii < ICHUNK; ++ii) {
    const int buf = ii & 1;
    if (ii + 1 < ICHUNK) stage(i0 + ii + 1, buf ^ 1);
    const int i = i0 + ii;
    float wf[64];  // W[o][i][dh*8 + j][k]
#pragma unroll
    for (int q = 0; q < 16; ++q) {
      const float4 v4 = lw4[buf][q * 65 + lane];
      wf[q * 4 + 0] = v4.x; wf[q * 4 + 1] = v4.y;
      wf[q * 4 + 2] = v4.z; wf[q * 4 + 3] = v4.w;
    }
#pragma unroll
    for (int bb = 0; bb < 4; ++bb) {
      const int b = b0 + wv * 4 + bb;
      const float4* pp = (const float4*)(pose + ((size_t)b * I_CAPS + i) * IDC);
      const float4 p0 = pp[0], p1 = pp[1];
      const float pk[8] = {p0.x, p0.y, p0.z, p0.w, p1.x, p1.y, p1.z, p1.w};
      float X[8];
#pragma unroll
      for (int j = 0; j < 8; ++j) {
        float s = 0.f;
#pragma unroll
        for (int k = 0; k < 8; ++k) s += wf[j * 8 + k] * pk[k];
        X[j] = s;
      }
      float c;
      if (MODE == 0) {
        c = 1.0f / 32.0f;
      } else {
        const float* vrow = vbuf + ((size_t)(b * O_CAPS + o) * OD) + dh * 8;
        float lg = 0.f;
#pragma unroll
        for (int j = 0; j < 8; ++j) lg += vrow[j] * X[j];
        lg += __shfl_xor(lg, 1, 64);  // full v.X over 16 d
        const size_t bidx = ((size_t)b * I_CAPS + i) * O_CAPS + o;
        if (MODE == 2) lg += blog[bidx];
        if (MODE == 1 && dh == 0) blog[bidx] = lg;
        float mx = lg;
#pragma unroll
        for (int s = 2; s < 64; s <<= 1) mx = fmaxf(mx, __shfl_xor(mx, s, 64));
        const float e = __expf(lg - mx);
        float sm = e;
#pragma unroll
        for (int s = 2; s < 64; s <<= 1) sm += __shfl_xor(sm, s, 64);
        c = e / sm;
      }
#pragma unroll
      for (int j = 0; j < 8; ++j) acc[bb][j] += c * X[j];
    }
    __syncthreads();
  }

  // partials: [chunk*4 + bg][bl 16][o*16 + dh*8 + j]
  const size_t pbase = ((size_t)blockIdx.x * 4 + blockIdx.y) * (16 * 512);
#pragma unroll
  for (int bb = 0; bb < 4; ++bb) {
    const int bl = wv * 4 + bb;
    float4* dst =
        (float4*)(partials + pbase + (size_t)bl * 512 + o * 16 + dh * 8);
    dst[0] = make_float4(acc[bb][0], acc[bb][1], acc[bb][2], acc[bb][3]);
    dst[1] = make_float4(acc[bb][4], acc[bb][5], acc[bb][6], acc[bb][7]);
  }
}

// ---------------------------------------------------------------------------
// Reduce partials over 256 i-chunks, squash over d -> dst[b][o][d]
// partials: [chunk*4 + bg][bl 16][od 512]
// ---------------------------------------------------------------------------
__global__ __launch_bounds__(256) void reduce_squash(
    const float* __restrict__ partials, float* __restrict__ dst) {
  const int t = blockIdx.x * 256 + threadIdx.x;  // (b, od)
  const int b = t >> 9;
  const int r = t & 511;
  const int bg = b >> 4, bl = b & 15;
  const size_t elem = (size_t)bl * 512 + r;
  float s = 0.f;
  for (int blk = 0; blk < NPBLK; ++blk)
    s += partials[(size_t)(blk * 4 + bg) * (16 * 512) + elem];
  float sq = s * s;
  sq += __shfl_xor(sq, 1, 64);
  sq += __shfl_xor(sq, 2, 64);
  sq += __shfl_xor(sq, 4, 64);
  sq += __shfl_xor(sq, 8, 64);
  const float sc = sq / (1.f + sq) / (sqrtf(sq) + 1e-8f);
  dst[t] = s * sc;
}

// ---------------------------------------------------------------------------
// VAE head
// ---------------------------------------------------------------------------
__global__ __launch_bounds__(256) void fc1_relu(
    const float* __restrict__ outc, const float* __restrict__ w1,
    const float* __restrict__ b1, float* __restrict__ h) {
  const int gid = blockIdx.x * 256 + threadIdx.x;
  const int n = gid >> 10, j = gid & 1023;
  float s = b1[j];
#pragma unroll
  for (int k = 0; k < 16; ++k) s += outc[n * 16 + k] * w1[k * 1024 + j];
  h[gid] = fmaxf(s, 0.f);
}

__global__ __launch_bounds__(256) void fc2_mu(
    const float* __restrict__ h, const float* __restrict__ w2,
    const float* __restrict__ b2, float* __restrict__ dout) {
  __shared__ float lh[4 * 1024];
  const int tid = threadIdx.x;
  const int nl = tid >> 6, m = tid & 63;
  const int n0 = blockIdx.x * 4;
  for (int idx = tid; idx < 4096; idx += 256)
    lh[idx] = h[(size_t)n0 * 1024 + idx];
  __syncthreads();
  float s = b2[m];
  const float* hr = lh + nl * 1024;
#pragma unroll 8
  for (int j = 0; j < 1024; ++j) s += hr[j] * w2[j * 64 + m];
  const int n = n0 + nl;
  dout[n * 64 + m] = s;
  dout[131072 + n * 64 + m] = s;
}

__global__ __launch_bounds__(256) void fc_var(
    const float* __restrict__ outc, const float* __restrict__ wv,
    const float* __restrict__ bv, float* __restrict__ dout) {
  const int gid = blockIdx.x * 256 + threadIdx.x;
  const int n = gid >> 6, m = gid & 63;
  float s = bv[m];
#pragma unroll
  for (int k = 0; k < 16; ++k) s += outc[n * 16 + k] * wv[k * 64 + m];
  const float sp = (s > 0.f) ? (s + log1pf(__expf(-s))) : log1pf(__expf(s));
  dout[262144 + gid] = sp + 1e-8f;
}

// ---------------------------------------------------------------------------
extern "C" void kernel_launch(void* const* d_in, const int* in_sizes, int n_in,
                              void* d_out, int out_size, void* d_ws,
                              size_t ws_size, hipStream_t stream) {
  const float* x = (const float*)d_in[0];
  const float* conv_w = (const float*)d_in[1];
  const float* bn_gamma = (const float*)d_in[2];
  const float* bn_beta = (const float*)d_in[3];
  const float* bn_mean = (const float*)d_in[4];
  const float* bn_var = (const float*)d_in[5];
  const float* caps_w = (const float*)d_in[6];
  const float* fcm_w1 = (const float*)d_in[7];
  const float* fcm_b1 = (const float*)d_in[8];
  const float* fcm_w2 = (const float*)d_in[9];
  const float* fcm_b2 = (const float*)d_in[10];
  const float* fcv_w = (const float*)d_in[11];
  const float* fcv_b = (const float*)d_in[12];
  float* out = (float*)d_out;
  float* ws = (float*)d_ws;

  float* pose = ws + OFF_POSE;
  float* blog = ws + OFF_BLOG;
  float* part = ws + OFF_PART;
  float* vbuf = ws + OFF_VBUF;
  float* outc = ws + OFF_OUTC;
  unsigned short* wbq = (unsigned short*)(ws + OFF_WB);
  float* bias = ws + OFF_BIAS;
  unsigned short* wr = (unsigned short*)(ws + OFF_WR);
  unsigned short* aim = (unsigned short*)(ws + OFF_AIM);
  float* h = ws + OFF_H;

  prep_wr<<<8192, 256, 0, stream>>>(caps_w, wr);
  prep_wb<<<512, 256, 0, stream>>>(conv_w, bn_gamma, bn_beta, bn_mean, bn_var,
                                   wbq, bias);
  prep_aim<<<dim3(64, 16), 256, 0, stream>>>(x, aim);
  conv_gemm<<<dim3(8, 64), 256, 0, stream>>>(aim, wbq, bias, pose);

  routing_phase<0><<<dim3(NPBLK, 4), 256, 0, stream>>>(
      pose, wr, nullptr, nullptr, part);
  reduce_squash<<<128, 256, 0, stream>>>(part, vbuf);

  routing_phase<1><<<dim3(NPBLK, 4), 256, 0, stream>>>(
      pose, wr, vbuf, blog, part);
  reduce_squash<<<128, 256, 0, stream>>>(part, vbuf);

  routing_phase<2><<<dim3(NPBLK, 4), 256, 0, stream>>>(
      pose, wr, vbuf, blog, part);
  reduce_squash<<<128, 256, 0, stream>>>(part, outc);

  fc1_relu<<<8192, 256, 0, stream>>>(outc, fcm_w1, fcm_b1, h);
  fc2_mu<<<512, 256, 0, stream>>>(h, fcm_w2, fcm_b2, out);
  fc_var<<<512, 256, 0, stream>>>(outc, fcv_w, fcv_b, out);
}

// Round 6
// 561.262 us; speedup vs baseline: 1.3179x; 1.3179x over previous
//
#include <hip/hip_runtime.h>
#include <cstdint>
#include <cstddef>

#define B 64
#define PCH 512
#define O_CAPS 32
#define OD 16
#define IDC 8
#define I_CAPS 4096
#define ICHUNK 16
#define NPBLK 256  // I_CAPS / ICHUNK
#define KDIM 4608  // 512*9

typedef __attribute__((ext_vector_type(8))) short bf16x8;
typedef __attribute__((ext_vector_type(4))) float f32x4;
typedef __attribute__((ext_vector_type(8))) unsigned short u16x8;

// workspace layout (in floats)
#define OFF_POSE 0
#define SZ_POSE (B * I_CAPS * IDC)                    // 2,097,152
#define OFF_BLOG (OFF_POSE + SZ_POSE)
#define SZ_BLOG ((size_t)B * I_CAPS * O_CAPS)         // 8,388,608
#define OFF_PART (OFF_BLOG + SZ_BLOG)
#define SZ_PART ((size_t)NPBLK * 4 * 16 * 512)        // 8,388,608
#define OFF_VBUF (OFF_PART + SZ_PART)
#define SZ_V (B * O_CAPS * OD)                        // 32,768
#define OFF_OUTC (OFF_VBUF + SZ_V)
#define OFF_WB (OFF_OUTC + SZ_V)                      // bf16 512*4608
#define OFF_BIAS (OFF_WB + (PCH * KDIM) / 2)
#define OFF_WR (OFF_BIAS + 512)                       // bf16 caps_w
#define SZ_WR ((size_t)O_CAPS * I_CAPS * OD * IDC / 2)  // 8,388,608 floats
// Aim (bf16, 9,437,184 float-equiv) aliases blog + head of part: dead before
// routing<0> writes part / routing<1> writes blog.
#define OFF_AIM OFF_BLOG
#define OFF_H OFF_BLOG  // h reuses blog after routing

__device__ inline unsigned short f2bf(float f) {
  union { float f; unsigned int u; } v; v.f = f;
  unsigned int r = v.u + 0x7fff + ((v.u >> 16) & 1);  // RNE
  return (unsigned short)(r >> 16);
}
__device__ inline float bf2f(unsigned short u) {
  union { unsigned int u; float f; } v; v.u = ((unsigned int)u) << 16;
  return v.f;
}

// ---------------------------------------------------------------------------
// prep_wr: caps_w fp32 -> bf16, same layout [o][i][d][k].
// ---------------------------------------------------------------------------
__global__ __launch_bounds__(256) void prep_wr(
    const float* __restrict__ cw, unsigned short* __restrict__ wr) {
  const size_t t = (size_t)blockIdx.x * 256 + threadIdx.x;  // 2,097,152
  const float4* s = (const float4*)cw + t * 2;
  const float4 a = s[0], b = s[1];
  u16x8 v;
  v[0] = f2bf(a.x); v[1] = f2bf(a.y); v[2] = f2bf(a.z); v[3] = f2bf(a.w);
  v[4] = f2bf(b.x); v[5] = f2bf(b.y); v[6] = f2bf(b.z); v[7] = f2bf(b.w);
  ((u16x8*)wr)[t] = v;
}

// ---------------------------------------------------------------------------
// prep_wb: Wb[n][k] = bf16(conv_w[n][k] * inv[n]); bias[n] = beta - mean*inv.
// ---------------------------------------------------------------------------
__global__ __launch_bounds__(256) void prep_wb(
    const float* __restrict__ cw, const float* __restrict__ gamma,
    const float* __restrict__ beta, const float* __restrict__ mean,
    const float* __restrict__ var, unsigned short* __restrict__ wb,
    float* __restrict__ bias) {
  const int n = blockIdx.x;
  const float inv = gamma[n] * rsqrtf(var[n] + 1e-5f);
  if (threadIdx.x == 0) bias[n] = beta[n] - mean[n] * inv;
  for (int k = threadIdx.x; k < KDIM; k += 256)
    wb[(size_t)n * KDIM + k] = f2bf(cw[(size_t)n * KDIM + k] * inv);
}

// ---------------------------------------------------------------------------
// prep_aim: im2col to bf16. Aim[m=(b,px)][k=ci*9+tap]
// ---------------------------------------------------------------------------
__global__ __launch_bounds__(256) void prep_aim(
    const float* __restrict__ x, unsigned short* __restrict__ aim) {
  __shared__ float lxp[32 * 100];
  const int b = blockIdx.x;
  const int ci0 = blockIdx.y * 32;
  const int tid = threadIdx.x;
  for (int t = tid; t < 3200; t += 256) lxp[t] = 0.f;
  __syncthreads();
  for (int t = tid; t < 2048; t += 256) {
    const int ci = t >> 6, px = t & 63;
    lxp[ci * 100 + 11 + (px >> 3) * 10 + (px & 7)] =
        x[((size_t)b * PCH + ci0 + ci) * 64 + px];
  }
  __syncthreads();
  for (int t = tid; t < 4608; t += 256) {
    const int px = t / 72;
    const int kk = (t - px * 72) * 4;
    unsigned short v[4];
#pragma unroll
    for (int j = 0; j < 4; ++j) {
      const int k = kk + j;
      const int ci = k / 9;
      const int tap = k - ci * 9;
      const int kh = tap / 3, kw = tap - kh * 3;
      v[j] = f2bf(lxp[ci * 100 + ((px >> 3) + kh) * 10 + (px & 7) + kw]);
    }
    ushort4* dst =
        (ushort4*)(aim + (size_t)(b * 64 + px) * KDIM + ci0 * 9 + kk);
    *dst = make_ushort4(v[0], v[1], v[2], v[3]);
  }
}

// ---------------------------------------------------------------------------
// conv_gemm: 64x64 tiles, mfma 16x16x32_bf16, global_load_lds staging with
// XOR swizzle, fused bias+ReLU+squash -> pose.
// ---------------------------------------------------------------------------
__global__ __launch_bounds__(256) void conv_gemm(
    const unsigned short* __restrict__ aim, const unsigned short* __restrict__ wb,
    const float* __restrict__ bias, float* __restrict__ pose) {
  __shared__ unsigned short lA[64 * 64];
  __shared__ unsigned short lB[64 * 64];
  const int tid = threadIdx.x;
  const int lane = tid & 63, wv = tid >> 6;
  const int wm = wv & 1, wn = wv >> 1;
  const int n0 = blockIdx.x * 64;
  const int m0 = blockIdx.y * 64;
  const int rsub = lane >> 3, seg = lane & 7;

  f32x4 acc[2][2];
#pragma unroll
  for (int a = 0; a < 2; ++a)
#pragma unroll
    for (int c = 0; c < 2; ++c) acc[a][c] = (f32x4){0.f, 0.f, 0.f, 0.f};

  for (int k0 = 0; k0 < KDIM; k0 += 64) {
    __syncthreads();
#pragma unroll
    for (int it = 0; it < 2; ++it) {
      const int r = it * 32 + wv * 8 + rsub;
      const int c = seg ^ (r & 7);
      const unsigned short* ga = aim + (size_t)(m0 + r) * KDIM + k0 + c * 8;
      __builtin_amdgcn_global_load_lds(
          (const __attribute__((address_space(1))) void*)ga,
          (__attribute__((address_space(3))) void*)(lA + (it * 32 + wv * 8) * 64),
          16, 0, 0);
      const unsigned short* gb = wb + (size_t)(n0 + r) * KDIM + k0 + c * 8;
      __builtin_amdgcn_global_load_lds(
          (const __attribute__((address_space(1))) void*)gb,
          (__attribute__((address_space(3))) void*)(lB + (it * 32 + wv * 8) * 64),
          16, 0, 0);
    }
    __syncthreads();
#pragma unroll
    for (int kc = 0; kc < 2; ++kc) {
      const int g = kc * 4 + (lane >> 4);
      const int ml = wm * 32 + (lane & 15);
      const int nl = wn * 32 + (lane & 15);
      const int sa = (g ^ (ml & 7)) * 8;
      const int sb = (g ^ (nl & 7)) * 8;
      const bf16x8 a0 = *(const bf16x8*)(lA + (ml + 0) * 64 + sa);
      const bf16x8 a1 = *(const bf16x8*)(lA + (ml + 16) * 64 + sa);
      const bf16x8 b0 = *(const bf16x8*)(lB + (nl + 0) * 64 + sb);
      const bf16x8 b1 = *(const bf16x8*)(lB + (nl + 16) * 64 + sb);
      acc[0][0] = __builtin_amdgcn_mfma_f32_16x16x32_bf16(a0, b0, acc[0][0], 0, 0, 0);
      acc[0][1] = __builtin_amdgcn_mfma_f32_16x16x32_bf16(a0, b1, acc[0][1], 0, 0, 0);
      acc[1][0] = __builtin_amdgcn_mfma_f32_16x16x32_bf16(a1, b0, acc[1][0], 0, 0, 0);
      acc[1][1] = __builtin_amdgcn_mfma_f32_16x16x32_bf16(a1, b1, acc[1][1], 0, 0, 0);
    }
  }

  const int bq = blockIdx.y;
  float bsv[2];
#pragma unroll
  for (int ni = 0; ni < 2; ++ni)
    bsv[ni] = bias[n0 + wn * 32 + ni * 16 + (lane & 15)];
#pragma unroll
  for (int mi = 0; mi < 2; ++mi) {
#pragma unroll
    for (int ni = 0; ni < 2; ++ni) {
      const int n = n0 + wn * 32 + ni * 16 + (lane & 15);
#pragma unroll
      for (int reg = 0; reg < 4; ++reg) {
        float v = fmaxf(acc[mi][ni][reg] + bsv[ni], 0.f);
        float s2 = v * v;
        s2 += __shfl_xor(s2, 1, 64);
        s2 += __shfl_xor(s2, 2, 64);
        s2 += __shfl_xor(s2, 4, 64);
        const float sc = s2 / (1.f + s2) / (sqrtf(s2) + 1e-8f);
        const int px = wm * 32 + mi * 16 + (lane >> 4) * 4 + reg;
        pose[((size_t)bq * I_CAPS + (n >> 3) * 64 + px) * IDC + (n & 7)] =
            v * sc;
      }
    }
  }
}

// ---------------------------------------------------------------------------
// Routing phase v4b: 256 threads = 4 waves, block = 16 i x 16 b. Wave owns
// 4 b, register acc[4][8]. W staged from bf16 (half traffic), fp32 in LDS
// (pitch-65 float4, conflict-free). Grid (256, 4) -> 1024 blocks.
// __launch_bounds__(256, 2): cap 256 VGPRs -- round 5's (256,4) capped at
// 128 and spilled wf[]/acc[] to scratch (~700 MB/dispatch HBM spill traffic,
// VALUBusy 19%). Natural allocation ~90-140 regs -> 3-5 waves/EU, no spill.
// ---------------------------------------------------------------------------
template <int MODE>
__global__ __launch_bounds__(256, 2) void routing_phase(
    const float* __restrict__ pose, const unsigned short* __restrict__ wr,
    const float* __restrict__ vbuf, float* __restrict__ blog,
    float* __restrict__ partials) {
  __shared__ float4 lw4[2][16 * 65];  // 2 x 16.6 KB (fp32 expanded)
  const int tid = threadIdx.x;
  const int lane = tid & 63;
  const int wv = tid >> 6;  // 0..3
  const int o = lane >> 1, dh = lane & 1;
  const int i0 = blockIdx.x * ICHUNK;
  const int b0 = blockIdx.y * 16;

  const int sl = tid >> 3;  // 0..31
  const int sq = tid & 7;   // 0..7

  float acc[4][8];
#pragma unroll
  for (int bb = 0; bb < 4; ++bb)
#pragma unroll
    for (int j = 0; j < 8; ++j) acc[bb][j] = 0.f;

  auto stage = [&](int i, int buf) {
#pragma unroll
    for (int half = 0; half < 2; ++half) {
      const int l = sl + half * 32;
      const u16x8 v = ((const u16x8*)wr)[(size_t)(l >> 1) * (I_CAPS * 16) +
                                         (size_t)i * 16 + (l & 1) * 8 + sq];
#pragma unroll
      for (int e = 0; e < 2; ++e) {
        float4 f;
        f.x = bf2f(v[e * 4 + 0]);
        f.y = bf2f(v[e * 4 + 1]);
        f.z = bf2f(v[e * 4 + 2]);
        f.w = bf2f(v[e * 4 + 3]);
        lw4[buf][(sq * 2 + e) * 65 + l] = f;
      }
    }
  };

  stage(i0, 0);
  __syncthreads();

  for (int ii = 0; ii < ICHUNK; ++ii) {
    const int buf = ii & 1;
    if (ii + 1 < ICHUNK) stage(i0 + ii + 1, buf ^ 1);
    const int i = i0 + ii;
    float wf[64];  // W[o][i][dh*8 + j][k]
#pragma unroll
    for (int q = 0; q < 16; ++q) {
      const float4 v4 = lw4[buf][q * 65 + lane];
      wf[q * 4 + 0] = v4.x; wf[q * 4 + 1] = v4.y;
      wf[q * 4 + 2] = v4.z; wf[q * 4 + 3] = v4.w;
    }
#pragma unroll
    for (int bb = 0; bb < 4; ++bb) {
      const int b = b0 + wv * 4 + bb;
      const float4* pp = (const float4*)(pose + ((size_t)b * I_CAPS + i) * IDC);
      const float4 p0 = pp[0], p1 = pp[1];
      const float pk[8] = {p0.x, p0.y, p0.z, p0.w, p1.x, p1.y, p1.z, p1.w};
      float X[8];
#pragma unroll
      for (int j = 0; j < 8; ++j) {
        float s = 0.f;
#pragma unroll
        for (int k = 0; k < 8; ++k) s += wf[j * 8 + k] * pk[k];
        X[j] = s;
      }
      float c;
      if (MODE == 0) {
        c = 1.0f / 32.0f;
      } else {
        const float* vrow = vbuf + ((size_t)(b * O_CAPS + o) * OD) + dh * 8;
        float lg = 0.f;
#pragma unroll
        for (int j = 0; j < 8; ++j) lg += vrow[j] * X[j];
        lg += __shfl_xor(lg, 1, 64);  // full v.X over 16 d
        const size_t bidx = ((size_t)b * I_CAPS + i) * O_CAPS + o;
        if (MODE == 2) lg += blog[bidx];
        if (MODE == 1 && dh == 0) blog[bidx] = lg;
        float mx = lg;
#pragma unroll
        for (int s = 2; s < 64; s <<= 1) mx = fmaxf(mx, __shfl_xor(mx, s, 64));
        const float e = __expf(lg - mx);
        float sm = e;
#pragma unroll
        for (int s = 2; s < 64; s <<= 1) sm += __shfl_xor(sm, s, 64);
        c = e / sm;
      }
#pragma unroll
      for (int j = 0; j < 8; ++j) acc[bb][j] += c * X[j];
    }
    __syncthreads();
  }

  // partials: [chunk*4 + bg][bl 16][o*16 + dh*8 + j]
  const size_t pbase = ((size_t)blockIdx.x * 4 + blockIdx.y) * (16 * 512);
#pragma unroll
  for (int bb = 0; bb < 4; ++bb) {
    const int bl = wv * 4 + bb;
    float4* dst =
        (float4*)(partials + pbase + (size_t)bl * 512 + o * 16 + dh * 8);
    dst[0] = make_float4(acc[bb][0], acc[bb][1], acc[bb][2], acc[bb][3]);
    dst[1] = make_float4(acc[bb][4], acc[bb][5], acc[bb][6], acc[bb][7]);
  }
}

// ---------------------------------------------------------------------------
// Reduce partials over 256 i-chunks, squash over d -> dst[b][o][d]
// ---------------------------------------------------------------------------
__global__ __launch_bounds__(256) void reduce_squash(
    const float* __restrict__ partials, float* __restrict__ dst) {
  const int t = blockIdx.x * 256 + threadIdx.x;  // (b, od)
  const int b = t >> 9;
  const int r = t & 511;
  const int bg = b >> 4, bl = b & 15;
  const size_t elem = (size_t)bl * 512 + r;
  float s = 0.f;
  for (int blk = 0; blk < NPBLK; ++blk)
    s += partials[(size_t)(blk * 4 + bg) * (16 * 512) + elem];
  float sq = s * s;
  sq += __shfl_xor(sq, 1, 64);
  sq += __shfl_xor(sq, 2, 64);
  sq += __shfl_xor(sq, 4, 64);
  sq += __shfl_xor(sq, 8, 64);
  const float sc = sq / (1.f + sq) / (sqrtf(sq) + 1e-8f);
  dst[t] = s * sc;
}

// ---------------------------------------------------------------------------
// VAE head
// ---------------------------------------------------------------------------
__global__ __launch_bounds__(256) void fc1_relu(
    const float* __restrict__ outc, const float* __restrict__ w1,
    const float* __restrict__ b1, float* __restrict__ h) {
  const int gid = blockIdx.x * 256 + threadIdx.x;
  const int n = gid >> 10, j = gid & 1023;
  float s = b1[j];
#pragma unroll
  for (int k = 0; k < 16; ++k) s += outc[n * 16 + k] * w1[k * 1024 + j];
  h[gid] = fmaxf(s, 0.f);
}

__global__ __launch_bounds__(256) void fc2_mu(
    const float* __restrict__ h, const float* __restrict__ w2,
    const float* __restrict__ b2, float* __restrict__ dout) {
  __shared__ float lh[4 * 1024];
  const int tid = threadIdx.x;
  const int nl = tid >> 6, m = tid & 63;
  const int n0 = blockIdx.x * 4;
  for (int idx = tid; idx < 4096; idx += 256)
    lh[idx] = h[(size_t)n0 * 1024 + idx];
  __syncthreads();
  float s = b2[m];
  const float* hr = lh + nl * 1024;
#pragma unroll 8
  for (int j = 0; j < 1024; ++j) s += hr[j] * w2[j * 64 + m];
  const int n = n0 + nl;
  dout[n * 64 + m] = s;
  dout[131072 + n * 64 + m] = s;
}

__global__ __launch_bounds__(256) void fc_var(
    const float* __restrict__ outc, const float* __restrict__ wv,
    const float* __restrict__ bv, float* __restrict__ dout) {
  const int gid = blockIdx.x * 256 + threadIdx.x;
  const int n = gid >> 6, m = gid & 63;
  float s = bv[m];
#pragma unroll
  for (int k = 0; k < 16; ++k) s += outc[n * 16 + k] * wv[k * 64 + m];
  const float sp = (s > 0.f) ? (s + log1pf(__expf(-s))) : log1pf(__expf(s));
  dout[262144 + gid] = sp + 1e-8f;
}

// ---------------------------------------------------------------------------
extern "C" void kernel_launch(void* const* d_in, const int* in_sizes, int n_in,
                              void* d_out, int out_size, void* d_ws,
                              size_t ws_size, hipStream_t stream) {
  const float* x = (const float*)d_in[0];
  const float* conv_w = (const float*)d_in[1];
  const float* bn_gamma = (const float*)d_in[2];
  const float* bn_beta = (const float*)d_in[3];
  const float* bn_mean = (const float*)d_in[4];
  const float* bn_var = (const float*)d_in[5];
  const float* caps_w = (const float*)d_in[6];
  const float* fcm_w1 = (const float*)d_in[7];
  const float* fcm_b1 = (const float*)d_in[8];
  const float* fcm_w2 = (const float*)d_in[9];
  const float* fcm_b2 = (const float*)d_in[10];
  const float* fcv_w = (const float*)d_in[11];
  const float* fcv_b = (const float*)d_in[12];
  float* out = (float*)d_out;
  float* ws = (float*)d_ws;

  float* pose = ws + OFF_POSE;
  float* blog = ws + OFF_BLOG;
  float* part = ws + OFF_PART;
  float* vbuf = ws + OFF_VBUF;
  float* outc = ws + OFF_OUTC;
  unsigned short* wbq = (unsigned short*)(ws + OFF_WB);
  float* bias = ws + OFF_BIAS;
  unsigned short* wr = (unsigned short*)(ws + OFF_WR);
  unsigned short* aim = (unsigned short*)(ws + OFF_AIM);
  float* h = ws + OFF_H;

  prep_wr<<<8192, 256, 0, stream>>>(caps_w, wr);
  prep_wb<<<512, 256, 0, stream>>>(conv_w, bn_gamma, bn_beta, bn_mean, bn_var,
                                   wbq, bias);
  prep_aim<<<dim3(64, 16), 256, 0, stream>>>(x, aim);
  conv_gemm<<<dim3(8, 64), 256, 0, stream>>>(aim, wbq, bias, pose);

  routing_phase<0><<<dim3(NPBLK, 4), 256, 0, stream>>>(
      pose, wr, nullptr, nullptr, part);
  reduce_squash<<<128, 256, 0, stream>>>(part, vbuf);

  routing_phase<1><<<dim3(NPBLK, 4), 256, 0, stream>>>(
      pose, wr, vbuf, blog, part);
  reduce_squash<<<128, 256, 0, stream>>>(part, vbuf);

  routing_phase<2><<<dim3(NPBLK, 4), 256, 0, stream>>>(
      pose, wr, vbuf, blog, part);
  reduce_squash<<<128, 256, 0, stream>>>(part, outc);

  fc1_relu<<<8192, 256, 0, stream>>>(outc, fcm_w1, fcm_b1, h);
  fc2_mu<<<512, 256, 0, stream>>>(h, fcm_w2, fcm_b2, out);
  fc_var<<<512, 256, 0, stream>>>(outc, fcv_w, fcv_b, out);
}

// Round 7
// 496.597 us; speedup vs baseline: 1.4895x; 1.1302x over previous
//
#include <hip/hip_runtime.h>
#include <cstdint>
#include <cstddef>

#define B 64
#define PCH 512
#define O_CAPS 32
#define OD 16
#define IDC 8
#define I_CAPS 4096
#define ICHUNK 16
#define NPBLK 256  // I_CAPS / ICHUNK
#define KDIM 4608  // 512*9

typedef __attribute__((ext_vector_type(8))) short bf16x8;
typedef __attribute__((ext_vector_type(4))) float f32x4;
typedef __attribute__((ext_vector_type(8))) unsigned short u16x8;

// workspace layout (in floats)
#define OFF_POSE 0
#define SZ_POSE (B * I_CAPS * IDC)                    // 2,097,152
#define OFF_BLOG (OFF_POSE + SZ_POSE)
#define SZ_BLOG ((size_t)B * I_CAPS * O_CAPS)         // 8,388,608
#define OFF_PART (OFF_BLOG + SZ_BLOG)
#define SZ_PART ((size_t)NPBLK * 4 * 16 * 512)        // 8,388,608
#define OFF_VBUF (OFF_PART + SZ_PART)
#define SZ_V (B * O_CAPS * OD)                        // 32,768
#define OFF_OUTC (OFF_VBUF + SZ_V)
#define OFF_WB (OFF_OUTC + SZ_V)                      // bf16 512*4608
#define OFF_BIAS (OFF_WB + (PCH * KDIM) / 2)
#define OFF_WR (OFF_BIAS + 512)                       // bf16 caps_w
#define SZ_WR ((size_t)O_CAPS * I_CAPS * OD * IDC / 2)  // 8,388,608 floats
// Aim (bf16, 9,437,184 float-equiv) aliases blog + head of part: dead before
// routing<0> writes part / routing<1> writes blog.
#define OFF_AIM OFF_BLOG
#define OFF_H OFF_BLOG  // h reuses blog after routing

__device__ inline unsigned short f2bf(float f) {
  union { float f; unsigned int u; } v; v.f = f;
  unsigned int r = v.u + 0x7fff + ((v.u >> 16) & 1);  // RNE
  return (unsigned short)(r >> 16);
}
__device__ inline float bf2f(unsigned short u) {
  union { unsigned int u; float f; } v; v.u = ((unsigned int)u) << 16;
  return v.f;
}

// ---------------------------------------------------------------------------
// prep_wr: caps_w fp32 -> bf16, same layout [o][i][d][k].
// ---------------------------------------------------------------------------
__global__ __launch_bounds__(256) void prep_wr(
    const float* __restrict__ cw, unsigned short* __restrict__ wr) {
  const size_t t = (size_t)blockIdx.x * 256 + threadIdx.x;  // 2,097,152
  const float4* s = (const float4*)cw + t * 2;
  const float4 a = s[0], b = s[1];
  u16x8 v;
  v[0] = f2bf(a.x); v[1] = f2bf(a.y); v[2] = f2bf(a.z); v[3] = f2bf(a.w);
  v[4] = f2bf(b.x); v[5] = f2bf(b.y); v[6] = f2bf(b.z); v[7] = f2bf(b.w);
  ((u16x8*)wr)[t] = v;
}

// ---------------------------------------------------------------------------
// prep_wb: Wb[n][k] = bf16(conv_w[n][k] * inv[n]); bias[n] = beta - mean*inv.
// ---------------------------------------------------------------------------
__global__ __launch_bounds__(256) void prep_wb(
    const float* __restrict__ cw, const float* __restrict__ gamma,
    const float* __restrict__ beta, const float* __restrict__ mean,
    const float* __restrict__ var, unsigned short* __restrict__ wb,
    float* __restrict__ bias) {
  const int n = blockIdx.x;
  const float inv = gamma[n] * rsqrtf(var[n] + 1e-5f);
  if (threadIdx.x == 0) bias[n] = beta[n] - mean[n] * inv;
  for (int k = threadIdx.x; k < KDIM; k += 256)
    wb[(size_t)n * KDIM + k] = f2bf(cw[(size_t)n * KDIM + k] * inv);
}

// ---------------------------------------------------------------------------
// prep_aim: im2col to bf16. Aim[m=(b,px)][k=ci*9+tap]
// ---------------------------------------------------------------------------
__global__ __launch_bounds__(256) void prep_aim(
    const float* __restrict__ x, unsigned short* __restrict__ aim) {
  __shared__ float lxp[32 * 100];
  const int b = blockIdx.x;
  const int ci0 = blockIdx.y * 32;
  const int tid = threadIdx.x;
  for (int t = tid; t < 3200; t += 256) lxp[t] = 0.f;
  __syncthreads();
  for (int t = tid; t < 2048; t += 256) {
    const int ci = t >> 6, px = t & 63;
    lxp[ci * 100 + 11 + (px >> 3) * 10 + (px & 7)] =
        x[((size_t)b * PCH + ci0 + ci) * 64 + px];
  }
  __syncthreads();
  for (int t = tid; t < 4608; t += 256) {
    const int px = t / 72;
    const int kk = (t - px * 72) * 4;
    unsigned short v[4];
#pragma unroll
    for (int j = 0; j < 4; ++j) {
      const int k = kk + j;
      const int ci = k / 9;
      const int tap = k - ci * 9;
      const int kh = tap / 3, kw = tap - kh * 3;
      v[j] = f2bf(lxp[ci * 100 + ((px >> 3) + kh) * 10 + (px & 7) + kw]);
    }
    ushort4* dst =
        (ushort4*)(aim + (size_t)(b * 64 + px) * KDIM + ci0 * 9 + kk);
    *dst = make_ushort4(v[0], v[1], v[2], v[3]);
  }
}

// ---------------------------------------------------------------------------
// conv_gemm: 64x64 tiles, mfma 16x16x32_bf16, global_load_lds staging with
// XOR swizzle, fused bias+ReLU+squash -> pose.
// ---------------------------------------------------------------------------
__global__ __launch_bounds__(256) void conv_gemm(
    const unsigned short* __restrict__ aim, const unsigned short* __restrict__ wb,
    const float* __restrict__ bias, float* __restrict__ pose) {
  __shared__ unsigned short lA[64 * 64];
  __shared__ unsigned short lB[64 * 64];
  const int tid = threadIdx.x;
  const int lane = tid & 63, wv = tid >> 6;
  const int wm = wv & 1, wn = wv >> 1;
  const int n0 = blockIdx.x * 64;
  const int m0 = blockIdx.y * 64;
  const int rsub = lane >> 3, seg = lane & 7;

  f32x4 acc[2][2];
#pragma unroll
  for (int a = 0; a < 2; ++a)
#pragma unroll
    for (int c = 0; c < 2; ++c) acc[a][c] = (f32x4){0.f, 0.f, 0.f, 0.f};

  for (int k0 = 0; k0 < KDIM; k0 += 64) {
    __syncthreads();
#pragma unroll
    for (int it = 0; it < 2; ++it) {
      const int r = it * 32 + wv * 8 + rsub;
      const int c = seg ^ (r & 7);
      const unsigned short* ga = aim + (size_t)(m0 + r) * KDIM + k0 + c * 8;
      __builtin_amdgcn_global_load_lds(
          (const __attribute__((address_space(1))) void*)ga,
          (__attribute__((address_space(3))) void*)(lA + (it * 32 + wv * 8) * 64),
          16, 0, 0);
      const unsigned short* gb = wb + (size_t)(n0 + r) * KDIM + k0 + c * 8;
      __builtin_amdgcn_global_load_lds(
          (const __attribute__((address_space(1))) void*)gb,
          (__attribute__((address_space(3))) void*)(lB + (it * 32 + wv * 8) * 64),
          16, 0, 0);
    }
    __syncthreads();
#pragma unroll
    for (int kc = 0; kc < 2; ++kc) {
      const int g = kc * 4 + (lane >> 4);
      const int ml = wm * 32 + (lane & 15);
      const int nl = wn * 32 + (lane & 15);
      const int sa = (g ^ (ml & 7)) * 8;
      const int sb = (g ^ (nl & 7)) * 8;
      const bf16x8 a0 = *(const bf16x8*)(lA + (ml + 0) * 64 + sa);
      const bf16x8 a1 = *(const bf16x8*)(lA + (ml + 16) * 64 + sa);
      const bf16x8 b0 = *(const bf16x8*)(lB + (nl + 0) * 64 + sb);
      const bf16x8 b1 = *(const bf16x8*)(lB + (nl + 16) * 64 + sb);
      acc[0][0] = __builtin_amdgcn_mfma_f32_16x16x32_bf16(a0, b0, acc[0][0], 0, 0, 0);
      acc[0][1] = __builtin_amdgcn_mfma_f32_16x16x32_bf16(a0, b1, acc[0][1], 0, 0, 0);
      acc[1][0] = __builtin_amdgcn_mfma_f32_16x16x32_bf16(a1, b0, acc[1][0], 0, 0, 0);
      acc[1][1] = __builtin_amdgcn_mfma_f32_16x16x32_bf16(a1, b1, acc[1][1], 0, 0, 0);
    }
  }

  const int bq = blockIdx.y;
  float bsv[2];
#pragma unroll
  for (int ni = 0; ni < 2; ++ni)
    bsv[ni] = bias[n0 + wn * 32 + ni * 16 + (lane & 15)];
#pragma unroll
  for (int mi = 0; mi < 2; ++mi) {
#pragma unroll
    for (int ni = 0; ni < 2; ++ni) {
      const int n = n0 + wn * 32 + ni * 16 + (lane & 15);
#pragma unroll
      for (int reg = 0; reg < 4; ++reg) {
        float v = fmaxf(acc[mi][ni][reg] + bsv[ni], 0.f);
        float s2 = v * v;
        s2 += __shfl_xor(s2, 1, 64);
        s2 += __shfl_xor(s2, 2, 64);
        s2 += __shfl_xor(s2, 4, 64);
        const float sc = s2 / (1.f + s2) / (sqrtf(s2) + 1e-8f);
        const int px = wm * 32 + mi * 16 + (lane >> 4) * 4 + reg;
        pose[((size_t)bq * I_CAPS + (n >> 3) * 64 + px) * IDC + (n & 7)] =
            v * sc;
      }
    }
  }
}

// ---------------------------------------------------------------------------
// Routing phase v5: v4b structure (256 thr, 4 waves, 4 b/wave, grid (256,4))
// with two DS-pipe cuts:
//  (a) W staged in LDS as raw bf16 u16x8 (pitch-65 swizzle, 2-way banking):
//      wf reads 16 -> 8 ds_read_b128, staging writes halved, LDS 33->17 KB
//      (higher block residency). bf16->fp32 unpack via shift/mask VALU.
//  (b) softmax WITHOUT max subtraction (|logit| <~ 3, exp can't overflow;
//      softmax shift-invariant): 11 -> 6 shuffles per (b,i).
// ---------------------------------------------------------------------------
template <int MODE>
__global__ __launch_bounds__(256, 2) void routing_phase(
    const float* __restrict__ pose, const unsigned short* __restrict__ wr,
    const float* __restrict__ vbuf, float* __restrict__ blog,
    float* __restrict__ partials) {
  __shared__ u16x8 lw[2][8 * 65];  // 2 x 8.3 KB
  const int tid = threadIdx.x;
  const int lane = tid & 63;
  const int wv = tid >> 6;  // 0..3
  const int o = lane >> 1, dh = lane & 1;
  const int i0 = blockIdx.x * ICHUNK;
  const int b0 = blockIdx.y * 16;

  const int sl = tid >> 3;  // 0..31
  const int sq = tid & 7;   // 0..7
  const u16x8* wr8 = (const u16x8*)wr;

  float acc[4][8];
#pragma unroll
  for (int bb = 0; bb < 4; ++bb)
#pragma unroll
    for (int j = 0; j < 8; ++j) acc[bb][j] = 0.f;

  // stage W slice for capsule i into buf (raw bf16; one b128 write per half)
  auto stage = [&](int i, int buf) {
#pragma unroll
    for (int half = 0; half < 2; ++half) {
      const int l = sl + half * 32;  // l = o*2+dh lane-slot
      lw[buf][sq * 65 + l] =
          wr8[(size_t)(l >> 1) * (I_CAPS * 16) + (size_t)i * 16 +
              (l & 1) * 8 + sq];
    }
  };

  stage(i0, 0);
  __syncthreads();

  for (int ii = 0; ii < ICHUNK; ++ii) {
    const int buf = ii & 1;
    if (ii + 1 < ICHUNK) stage(i0 + ii + 1, buf ^ 1);
    const int i = i0 + ii;
    float wf[64];  // W[o][i][dh*8 + j][k] fp32-expanded
#pragma unroll
    for (int q = 0; q < 8; ++q) {
      const u16x8 v = lw[buf][q * 65 + lane];
      const unsigned int* du = (const unsigned int*)&v;
#pragma unroll
      for (int w = 0; w < 4; ++w) {
        const unsigned int d = du[w];
        wf[q * 8 + w * 2 + 0] = __uint_as_float(d << 16);
        wf[q * 8 + w * 2 + 1] = __uint_as_float(d & 0xffff0000u);
      }
    }
#pragma unroll
    for (int bb = 0; bb < 4; ++bb) {
      const int b = b0 + wv * 4 + bb;
      const float4* pp = (const float4*)(pose + ((size_t)b * I_CAPS + i) * IDC);
      const float4 p0 = pp[0], p1 = pp[1];
      const float pk[8] = {p0.x, p0.y, p0.z, p0.w, p1.x, p1.y, p1.z, p1.w};
      float X[8];
#pragma unroll
      for (int j = 0; j < 8; ++j) {
        float s = 0.f;
#pragma unroll
        for (int k = 0; k < 8; ++k) s += wf[j * 8 + k] * pk[k];
        X[j] = s;
      }
      float c;
      if (MODE == 0) {
        c = 1.0f / 32.0f;
      } else {
        const float* vrow = vbuf + ((size_t)(b * O_CAPS + o) * OD) + dh * 8;
        float lg = 0.f;
#pragma unroll
        for (int j = 0; j < 8; ++j) lg += vrow[j] * X[j];
        lg += __shfl_xor(lg, 1, 64);  // full v.X over 16 d
        const size_t bidx = ((size_t)b * I_CAPS + i) * O_CAPS + o;
        if (MODE == 2) lg += blog[bidx];
        if (MODE == 1 && dh == 0) blog[bidx] = lg;
        // softmax without max-subtract: |lg| small, exp safe; shift-invariant
        const float e = __expf(lg);
        float sm = e;
#pragma unroll
        for (int s = 2; s < 64; s <<= 1) sm += __shfl_xor(sm, s, 64);
        c = e / sm;
      }
#pragma unroll
      for (int j = 0; j < 8; ++j) acc[bb][j] += c * X[j];
    }
    __syncthreads();
  }

  // partials: [chunk*4 + bg][bl 16][o*16 + dh*8 + j]
  const size_t pbase = ((size_t)blockIdx.x * 4 + blockIdx.y) * (16 * 512);
#pragma unroll
  for (int bb = 0; bb < 4; ++bb) {
    const int bl = wv * 4 + bb;
    float4* dst =
        (float4*)(partials + pbase + (size_t)bl * 512 + o * 16 + dh * 8);
    dst[0] = make_float4(acc[bb][0], acc[bb][1], acc[bb][2], acc[bb][3]);
    dst[1] = make_float4(acc[bb][4], acc[bb][5], acc[bb][6], acc[bb][7]);
  }
}

// ---------------------------------------------------------------------------
// Reduce partials over 256 i-chunks, squash over d -> dst[b][o][d]
// ---------------------------------------------------------------------------
__global__ __launch_bounds__(256) void reduce_squash(
    const float* __restrict__ partials, float* __restrict__ dst) {
  const int t = blockIdx.x * 256 + threadIdx.x;  // (b, od)
  const int b = t >> 9;
  const int r = t & 511;
  const int bg = b >> 4, bl = b & 15;
  const size_t elem = (size_t)bl * 512 + r;
  float s = 0.f;
  for (int blk = 0; blk < NPBLK; ++blk)
    s += partials[(size_t)(blk * 4 + bg) * (16 * 512) + elem];
  float sq = s * s;
  sq += __shfl_xor(sq, 1, 64);
  sq += __shfl_xor(sq, 2, 64);
  sq += __shfl_xor(sq, 4, 64);
  sq += __shfl_xor(sq, 8, 64);
  const float sc = sq / (1.f + sq) / (sqrtf(sq) + 1e-8f);
  dst[t] = s * sc;
}

// ---------------------------------------------------------------------------
// VAE head
// ---------------------------------------------------------------------------
__global__ __launch_bounds__(256) void fc1_relu(
    const float* __restrict__ outc, const float* __restrict__ w1,
    const float* __restrict__ b1, float* __restrict__ h) {
  const int gid = blockIdx.x * 256 + threadIdx.x;
  const int n = gid >> 10, j = gid & 1023;
  float s = b1[j];
#pragma unroll
  for (int k = 0; k < 16; ++k) s += outc[n * 16 + k] * w1[k * 1024 + j];
  h[gid] = fmaxf(s, 0.f);
}

__global__ __launch_bounds__(256) void fc2_mu(
    const float* __restrict__ h, const float* __restrict__ w2,
    const float* __restrict__ b2, float* __restrict__ dout) {
  __shared__ float lh[4 * 1024];
  const int tid = threadIdx.x;
  const int nl = tid >> 6, m = tid & 63;
  const int n0 = blockIdx.x * 4;
  for (int idx = tid; idx < 4096; idx += 256)
    lh[idx] = h[(size_t)n0 * 1024 + idx];
  __syncthreads();
  float s = b2[m];
  const float* hr = lh + nl * 1024;
#pragma unroll 8
  for (int j = 0; j < 1024; ++j) s += hr[j] * w2[j * 64 + m];
  const int n = n0 + nl;
  dout[n * 64 + m] = s;
  dout[131072 + n * 64 + m] = s;
}

__global__ __launch_bounds__(256) void fc_var(
    const float* __restrict__ outc, const float* __restrict__ wv,
    const float* __restrict__ bv, float* __restrict__ dout) {
  const int gid = blockIdx.x * 256 + threadIdx.x;
  const int n = gid >> 6, m = gid & 63;
  float s = bv[m];
#pragma unroll
  for (int k = 0; k < 16; ++k) s += outc[n * 16 + k] * wv[k * 64 + m];
  const float sp = (s > 0.f) ? (s + log1pf(__expf(-s))) : log1pf(__expf(s));
  dout[262144 + gid] = sp + 1e-8f;
}

// ---------------------------------------------------------------------------
extern "C" void kernel_launch(void* const* d_in, const int* in_sizes, int n_in,
                              void* d_out, int out_size, void* d_ws,
                              size_t ws_size, hipStream_t stream) {
  const float* x = (const float*)d_in[0];
  const float* conv_w = (const float*)d_in[1];
  const float* bn_gamma = (const float*)d_in[2];
  const float* bn_beta = (const float*)d_in[3];
  const float* bn_mean = (const float*)d_in[4];
  const float* bn_var = (const float*)d_in[5];
  const float* caps_w = (const float*)d_in[6];
  const float* fcm_w1 = (const float*)d_in[7];
  const float* fcm_b1 = (const float*)d_in[8];
  const float* fcm_w2 = (const float*)d_in[9];
  const float* fcm_b2 = (const float*)d_in[10];
  const float* fcv_w = (const float*)d_in[11];
  const float* fcv_b = (const float*)d_in[12];
  float* out = (float*)d_out;
  float* ws = (float*)d_ws;

  float* pose = ws + OFF_POSE;
  float* blog = ws + OFF_BLOG;
  float* part = ws + OFF_PART;
  float* vbuf = ws + OFF_VBUF;
  float* outc = ws + OFF_OUTC;
  unsigned short* wbq = (unsigned short*)(ws + OFF_WB);
  float* bias = ws + OFF_BIAS;
  unsigned short* wr = (unsigned short*)(ws + OFF_WR);
  unsigned short* aim = (unsigned short*)(ws + OFF_AIM);
  float* h = ws + OFF_H;

  prep_wr<<<8192, 256, 0, stream>>>(caps_w, wr);
  prep_wb<<<512, 256, 0, stream>>>(conv_w, bn_gamma, bn_beta, bn_mean, bn_var,
                                   wbq, bias);
  prep_aim<<<dim3(64, 16), 256, 0, stream>>>(x, aim);
  conv_gemm<<<dim3(8, 64), 256, 0, stream>>>(aim, wbq, bias, pose);

  routing_phase<0><<<dim3(NPBLK, 4), 256, 0, stream>>>(
      pose, wr, nullptr, nullptr, part);
  reduce_squash<<<128, 256, 0, stream>>>(part, vbuf);

  routing_phase<1><<<dim3(NPBLK, 4), 256, 0, stream>>>(
      pose, wr, vbuf, blog, part);
  reduce_squash<<<128, 256, 0, stream>>>(part, vbuf);

  routing_phase<2><<<dim3(NPBLK, 4), 256, 0, stream>>>(
      pose, wr, vbuf, blog, part);
  reduce_squash<<<128, 256, 0, stream>>>(part, outc);

  fc1_relu<<<8192, 256, 0, stream>>>(outc, fcm_w1, fcm_b1, h);
  fc2_mu<<<512, 256, 0, stream>>>(h, fcm_w2, fcm_b2, out);
  fc_var<<<512, 256, 0, stream>>>(outc, fcv_w, fcv_b, out);
}

// Round 8
// 463.478 us; speedup vs baseline: 1.5959x; 1.0715x over previous
//
#include <hip/hip_runtime.h>
#include <cstdint>
#include <cstddef>

#define B 64
#define PCH 512
#define O_CAPS 32
#define OD 16
#define IDC 8
#define I_CAPS 4096
#define ICHUNK 16
#define NPBLK 256  // I_CAPS / ICHUNK
#define KDIM 4608  // 512*9

typedef __attribute__((ext_vector_type(8))) short bf16x8;
typedef __attribute__((ext_vector_type(4))) float f32x4;
typedef __attribute__((ext_vector_type(8))) unsigned short u16x8;

// workspace layout (in floats)
#define OFF_POSE 0
#define SZ_POSE (B * I_CAPS * IDC)                    // 2,097,152
#define OFF_BLOG (OFF_POSE + SZ_POSE)
#define SZ_BLOG ((size_t)B * I_CAPS * O_CAPS)         // 8,388,608
#define OFF_PART (OFF_BLOG + SZ_BLOG)
#define SZ_PART ((size_t)NPBLK * 4 * 16 * 512)        // 8,388,608
#define OFF_VBUF (OFF_PART + SZ_PART)
#define SZ_V (B * O_CAPS * OD)                        // 32,768
#define OFF_OUTC (OFF_VBUF + SZ_V)
#define OFF_WB (OFF_OUTC + SZ_V)                      // bf16 512*4608
#define OFF_BIAS (OFF_WB + (PCH * KDIM) / 2)
#define OFF_WR (OFF_BIAS + 512)                       // bf16 caps_w
#define SZ_WR ((size_t)O_CAPS * I_CAPS * OD * IDC / 2)  // 8,388,608 floats
// Aim (bf16, 9,437,184 float-equiv) aliases blog + 1M head of part: dead
// before caps_v0 writes part_v0 / routing<1> writes blog.
#define OFF_AIM OFF_BLOG
// caps_v0 partials [32][64][512] fp32 = 1,048,576 floats at part head
#define OFF_PV0 OFF_PART
#define SZ_PV0 (32 * 64 * 512)
// pose in bf16 (2M elems = 1M float-equiv), after pv0; dead before phase<1>
#define OFF_PBF (OFF_PART + SZ_PV0)
#define OFF_H OFF_BLOG  // h reuses blog after routing

__device__ inline unsigned short f2bf(float f) {
  union { float f; unsigned int u; } v; v.f = f;
  unsigned int r = v.u + 0x7fff + ((v.u >> 16) & 1);  // RNE
  return (unsigned short)(r >> 16);
}

// ---------------------------------------------------------------------------
// cast_bf16x8 (was prep_wr): fp32 -> bf16 flat copy, 8 elems/thread.
// Used for caps_w -> wr and pose -> posebf.
// ---------------------------------------------------------------------------
__global__ __launch_bounds__(256) void cast_bf16x8(
    const float* __restrict__ src, unsigned short* __restrict__ dst) {
  const size_t t = (size_t)blockIdx.x * 256 + threadIdx.x;
  const float4* s = (const float4*)src + t * 2;
  const float4 a = s[0], b = s[1];
  u16x8 v;
  v[0] = f2bf(a.x); v[1] = f2bf(a.y); v[2] = f2bf(a.z); v[3] = f2bf(a.w);
  v[4] = f2bf(b.x); v[5] = f2bf(b.y); v[6] = f2bf(b.z); v[7] = f2bf(b.w);
  ((u16x8*)dst)[t] = v;
}

// ---------------------------------------------------------------------------
// prep_wb: Wb[n][k] = bf16(conv_w[n][k] * inv[n]); bias[n] = beta - mean*inv.
// ---------------------------------------------------------------------------
__global__ __launch_bounds__(256) void prep_wb(
    const float* __restrict__ cw, const float* __restrict__ gamma,
    const float* __restrict__ beta, const float* __restrict__ mean,
    const float* __restrict__ var, unsigned short* __restrict__ wb,
    float* __restrict__ bias) {
  const int n = blockIdx.x;
  const float inv = gamma[n] * rsqrtf(var[n] + 1e-5f);
  if (threadIdx.x == 0) bias[n] = beta[n] - mean[n] * inv;
  for (int k = threadIdx.x; k < KDIM; k += 256)
    wb[(size_t)n * KDIM + k] = f2bf(cw[(size_t)n * KDIM + k] * inv);
}

// ---------------------------------------------------------------------------
// prep_aim: im2col to bf16. Aim[m=(b,px)][k=ci*9+tap]
// ---------------------------------------------------------------------------
__global__ __launch_bounds__(256) void prep_aim(
    const float* __restrict__ x, unsigned short* __restrict__ aim) {
  __shared__ float lxp[32 * 100];
  const int b = blockIdx.x;
  const int ci0 = blockIdx.y * 32;
  const int tid = threadIdx.x;
  for (int t = tid; t < 3200; t += 256) lxp[t] = 0.f;
  __syncthreads();
  for (int t = tid; t < 2048; t += 256) {
    const int ci = t >> 6, px = t & 63;
    lxp[ci * 100 + 11 + (px >> 3) * 10 + (px & 7)] =
        x[((size_t)b * PCH + ci0 + ci) * 64 + px];
  }
  __syncthreads();
  for (int t = tid; t < 4608; t += 256) {
    const int px = t / 72;
    const int kk = (t - px * 72) * 4;
    unsigned short v[4];
#pragma unroll
    for (int j = 0; j < 4; ++j) {
      const int k = kk + j;
      const int ci = k / 9;
      const int tap = k - ci * 9;
      const int kh = tap / 3, kw = tap - kh * 3;
      v[j] = f2bf(lxp[ci * 100 + ((px >> 3) + kh) * 10 + (px & 7) + kw]);
    }
    ushort4* dst =
        (ushort4*)(aim + (size_t)(b * 64 + px) * KDIM + ci0 * 9 + kk);
    *dst = make_ushort4(v[0], v[1], v[2], v[3]);
  }
}

// ---------------------------------------------------------------------------
// conv_gemm: 64x64 tiles, mfma 16x16x32_bf16, global_load_lds staging with
// XOR swizzle, fused bias+ReLU+squash -> pose.
// GRID SWAPPED to (64 m, 8 n): blocks sharing an m-tile (same Aim slice) are
// 64 apart in linear id -> same XCD under round-robin -> Aim L2-resident
// (was: 8 n-blocks of one m-tile spread across all 8 XCDs = 8x HBM refetch).
// ---------------------------------------------------------------------------
__global__ __launch_bounds__(256) void conv_gemm(
    const unsigned short* __restrict__ aim, const unsigned short* __restrict__ wb,
    const float* __restrict__ bias, float* __restrict__ pose) {
  __shared__ unsigned short lA[64 * 64];
  __shared__ unsigned short lB[64 * 64];
  const int tid = threadIdx.x;
  const int lane = tid & 63, wv = tid >> 6;
  const int wm = wv & 1, wn = wv >> 1;
  const int m0 = blockIdx.x * 64;  // = batch * 64
  const int n0 = blockIdx.y * 64;
  const int rsub = lane >> 3, seg = lane & 7;

  f32x4 acc[2][2];
#pragma unroll
  for (int a = 0; a < 2; ++a)
#pragma unroll
    for (int c = 0; c < 2; ++c) acc[a][c] = (f32x4){0.f, 0.f, 0.f, 0.f};

  for (int k0 = 0; k0 < KDIM; k0 += 64) {
    __syncthreads();
#pragma unroll
    for (int it = 0; it < 2; ++it) {
      const int r = it * 32 + wv * 8 + rsub;
      const int c = seg ^ (r & 7);
      const unsigned short* ga = aim + (size_t)(m0 + r) * KDIM + k0 + c * 8;
      __builtin_amdgcn_global_load_lds(
          (const __attribute__((address_space(1))) void*)ga,
          (__attribute__((address_space(3))) void*)(lA + (it * 32 + wv * 8) * 64),
          16, 0, 0);
      const unsigned short* gb = wb + (size_t)(n0 + r) * KDIM + k0 + c * 8;
      __builtin_amdgcn_global_load_lds(
          (const __attribute__((address_space(1))) void*)gb,
          (__attribute__((address_space(3))) void*)(lB + (it * 32 + wv * 8) * 64),
          16, 0, 0);
    }
    __syncthreads();
#pragma unroll
    for (int kc = 0; kc < 2; ++kc) {
      const int g = kc * 4 + (lane >> 4);
      const int ml = wm * 32 + (lane & 15);
      const int nl = wn * 32 + (lane & 15);
      const int sa = (g ^ (ml & 7)) * 8;
      const int sb = (g ^ (nl & 7)) * 8;
      const bf16x8 a0 = *(const bf16x8*)(lA + (ml + 0) * 64 + sa);
      const bf16x8 a1 = *(const bf16x8*)(lA + (ml + 16) * 64 + sa);
      const bf16x8 b0 = *(const bf16x8*)(lB + (nl + 0) * 64 + sb);
      const bf16x8 b1 = *(const bf16x8*)(lB + (nl + 16) * 64 + sb);
      acc[0][0] = __builtin_amdgcn_mfma_f32_16x16x32_bf16(a0, b0, acc[0][0], 0, 0, 0);
      acc[0][1] = __builtin_amdgcn_mfma_f32_16x16x32_bf16(a0, b1, acc[0][1], 0, 0, 0);
      acc[1][0] = __builtin_amdgcn_mfma_f32_16x16x32_bf16(a1, b0, acc[1][0], 0, 0, 0);
      acc[1][1] = __builtin_amdgcn_mfma_f32_16x16x32_bf16(a1, b1, acc[1][1], 0, 0, 0);
    }
  }

  const int bq = blockIdx.x;
  float bsv[2];
#pragma unroll
  for (int ni = 0; ni < 2; ++ni)
    bsv[ni] = bias[n0 + wn * 32 + ni * 16 + (lane & 15)];
#pragma unroll
  for (int mi = 0; mi < 2; ++mi) {
#pragma unroll
    for (int ni = 0; ni < 2; ++ni) {
      const int n = n0 + wn * 32 + ni * 16 + (lane & 15);
#pragma unroll
      for (int reg = 0; reg < 4; ++reg) {
        float v = fmaxf(acc[mi][ni][reg] + bsv[ni], 0.f);
        float s2 = v * v;
        s2 += __shfl_xor(s2, 1, 64);
        s2 += __shfl_xor(s2, 2, 64);
        s2 += __shfl_xor(s2, 4, 64);
        const float sc = s2 / (1.f + s2) / (sqrtf(s2) + 1e-8f);
        const int px = wm * 32 + mi * 16 + (lane >> 4) * 4 + reg;
        pose[((size_t)bq * I_CAPS + (n >> 3) * 64 + px) * IDC + (n & 7)] =
            v * sc;
      }
    }
  }
}

// ---------------------------------------------------------------------------
// caps_v0: phase-0 routing as MFMA GEMM. c == 1/32 uniform =>
// out0[b][(o,d)] = squash_d( (1/32) * sum_{i,k} W[o,i,d,k] * p[b,i,k] ):
// C[M=64 b][N=512 (o,d)] = posebf[b][K=32768 (i,k)] . Wt[n][K]^T.
// Wt rows gathered on the fly from wr's [o][i][d][k] layout (for fixed (o,i),
// the d*8+k block is 256 B contiguous -> coalesced 1KB/wave reads).
// Grid (8 n-tiles, 32 k-splits); partials [ks][64][512] -> reduce_v0.
// ---------------------------------------------------------------------------
__global__ __launch_bounds__(256) void caps_v0(
    const unsigned short* __restrict__ posebf,
    const unsigned short* __restrict__ wr, float* __restrict__ pv0) {
  __shared__ unsigned short lA[64 * 64];
  __shared__ unsigned short lB[64 * 64];
  const int tid = threadIdx.x;
  const int lane = tid & 63, wv = tid >> 6;
  const int wm = wv & 1, wn = wv >> 1;
  const int o0 = blockIdx.x * 4;   // n-tile covers o0..o0+3 (x16 d)
  const int ks = blockIdx.y;       // K-chunk of 1024 (128 i)
  const int rsub = lane >> 3, seg = lane & 7;

  f32x4 acc[2][2];
#pragma unroll
  for (int a = 0; a < 2; ++a)
#pragma unroll
    for (int c = 0; c < 2; ++c) acc[a][c] = (f32x4){0.f, 0.f, 0.f, 0.f};

  for (int kt = 0; kt < 16; ++kt) {
    const int k0 = ks * 1024 + kt * 64;  // K base (8 i x 8 k)
    const int i0 = k0 >> 3;
    __syncthreads();
    // A: pose rows b=0..63, global_load_lds with XOR swizzle
#pragma unroll
    for (int it = 0; it < 2; ++it) {
      const int r = it * 32 + wv * 8 + rsub;
      const int c = seg ^ (r & 7);
      const unsigned short* ga = posebf + (size_t)r * 32768 + k0 + c * 8;
      __builtin_amdgcn_global_load_lds(
          (const __attribute__((address_space(1))) void*)ga,
          (__attribute__((address_space(3))) void*)(lA + (it * 32 + wv * 8) * 64),
          16, 0, 0);
    }
    // B: gather 64 n-rows (o,d) x 64 K-cols (i,k) from wr; plain LDS writes
#pragma unroll
    for (int h = 0; h < 2; ++h) {
      const int idx = h * 256 + tid;  // (ol, il, d)
      const int d = idx & 15;
      const int il = (idx >> 4) & 7;
      const int ol = idx >> 7;
      const u16x8 v = *(const u16x8*)(wr + (size_t)(o0 + ol) * 524288 +
                                      (size_t)(i0 + il) * 128 + d * 8);
      const int np = ol * 16 + d;
      *(u16x8*)(lB + np * 64 + (il ^ (np & 7)) * 8) = v;
    }
    __syncthreads();
#pragma unroll
    for (int kc = 0; kc < 2; ++kc) {
      const int g = kc * 4 + (lane >> 4);
      const int ml = wm * 32 + (lane & 15);
      const int nl = wn * 32 + (lane & 15);
      const int sa = (g ^ (ml & 7)) * 8;
      const int sb = (g ^ (nl & 7)) * 8;
      const bf16x8 a0 = *(const bf16x8*)(lA + (ml + 0) * 64 + sa);
      const bf16x8 a1 = *(const bf16x8*)(lA + (ml + 16) * 64 + sa);
      const bf16x8 b0 = *(const bf16x8*)(lB + (nl + 0) * 64 + sb);
      const bf16x8 b1 = *(const bf16x8*)(lB + (nl + 16) * 64 + sb);
      acc[0][0] = __builtin_amdgcn_mfma_f32_16x16x32_bf16(a0, b0, acc[0][0], 0, 0, 0);
      acc[0][1] = __builtin_amdgcn_mfma_f32_16x16x32_bf16(a0, b1, acc[0][1], 0, 0, 0);
      acc[1][0] = __builtin_amdgcn_mfma_f32_16x16x32_bf16(a1, b0, acc[1][0], 0, 0, 0);
      acc[1][1] = __builtin_amdgcn_mfma_f32_16x16x32_bf16(a1, b1, acc[1][1], 0, 0, 0);
    }
  }
#pragma unroll
  for (int mi = 0; mi < 2; ++mi) {
#pragma unroll
    for (int ni = 0; ni < 2; ++ni) {
      const int n = blockIdx.x * 64 + wn * 32 + ni * 16 + (lane & 15);
#pragma unroll
      for (int reg = 0; reg < 4; ++reg) {
        const int m = wm * 32 + mi * 16 + (lane >> 4) * 4 + reg;
        pv0[(size_t)(ks * 64 + m) * 512 + n] = acc[mi][ni][reg];
      }
    }
  }
}

// ---------------------------------------------------------------------------
// reduce_v0: sum 32 k-split partials, scale by 1/32 (uniform c), squash over
// d (= lane&15) -> vbuf[b][o][d].
// ---------------------------------------------------------------------------
__global__ __launch_bounds__(256) void reduce_v0(
    const float* __restrict__ pv0, float* __restrict__ vbuf) {
  const int t = blockIdx.x * 256 + threadIdx.x;  // (b, o*16+d)
  const int b = t >> 9;
  const int r = t & 511;
  float s = 0.f;
#pragma unroll 8
  for (int ks = 0; ks < 32; ++ks)
    s += pv0[(size_t)(ks * 64 + b) * 512 + r];
  s *= (1.0f / 32.0f);
  float sq = s * s;
  sq += __shfl_xor(sq, 1, 64);
  sq += __shfl_xor(sq, 2, 64);
  sq += __shfl_xor(sq, 4, 64);
  sq += __shfl_xor(sq, 8, 64);
  const float sc = sq / (1.f + sq) / (sqrtf(sq) + 1e-8f);
  vbuf[t] = s * sc;
}

// ---------------------------------------------------------------------------
// Routing phase v5 (unchanged): 256 thr, 4 waves x 4 b, register acc,
// bf16 LDS W (pitch-65), softmax without max-subtract.
// ---------------------------------------------------------------------------
template <int MODE>
__global__ __launch_bounds__(256, 2) void routing_phase(
    const float* __restrict__ pose, const unsigned short* __restrict__ wr,
    const float* __restrict__ vbuf, float* __restrict__ blog,
    float* __restrict__ partials) {
  __shared__ u16x8 lw[2][8 * 65];  // 2 x 8.3 KB
  const int tid = threadIdx.x;
  const int lane = tid & 63;
  const int wv = tid >> 6;
  const int o = lane >> 1, dh = lane & 1;
  const int i0 = blockIdx.x * ICHUNK;
  const int b0 = blockIdx.y * 16;

  const int sl = tid >> 3;
  const int sq = tid & 7;
  const u16x8* wr8 = (const u16x8*)wr;

  float acc[4][8];
#pragma unroll
  for (int bb = 0; bb < 4; ++bb)
#pragma unroll
    for (int j = 0; j < 8; ++j) acc[bb][j] = 0.f;

  auto stage = [&](int i, int buf) {
#pragma unroll
    for (int half = 0; half < 2; ++half) {
      const int l = sl + half * 32;
      lw[buf][sq * 65 + l] =
          wr8[(size_t)(l >> 1) * (I_CAPS * 16) + (size_t)i * 16 +
              (l & 1) * 8 + sq];
    }
  };

  stage(i0, 0);
  __syncthreads();

  for (int ii = 0; ii < ICHUNK; ++ii) {
    const int buf = ii & 1;
    if (ii + 1 < ICHUNK) stage(i0 + ii + 1, buf ^ 1);
    const int i = i0 + ii;
    float wf[64];
#pragma unroll
    for (int q = 0; q < 8; ++q) {
      const u16x8 v = lw[buf][q * 65 + lane];
      const unsigned int* du = (const unsigned int*)&v;
#pragma unroll
      for (int w = 0; w < 4; ++w) {
        const unsigned int d = du[w];
        wf[q * 8 + w * 2 + 0] = __uint_as_float(d << 16);
        wf[q * 8 + w * 2 + 1] = __uint_as_float(d & 0xffff0000u);
      }
    }
#pragma unroll
    for (int bb = 0; bb < 4; ++bb) {
      const int b = b0 + wv * 4 + bb;
      const float4* pp = (const float4*)(pose + ((size_t)b * I_CAPS + i) * IDC);
      const float4 p0 = pp[0], p1 = pp[1];
      const float pk[8] = {p0.x, p0.y, p0.z, p0.w, p1.x, p1.y, p1.z, p1.w};
      float X[8];
#pragma unroll
      for (int j = 0; j < 8; ++j) {
        float s = 0.f;
#pragma unroll
        for (int k = 0; k < 8; ++k) s += wf[j * 8 + k] * pk[k];
        X[j] = s;
      }
      const float* vrow = vbuf + ((size_t)(b * O_CAPS + o) * OD) + dh * 8;
      float lg = 0.f;
#pragma unroll
      for (int j = 0; j < 8; ++j) lg += vrow[j] * X[j];
      lg += __shfl_xor(lg, 1, 64);  // full v.X over 16 d
      const size_t bidx = ((size_t)b * I_CAPS + i) * O_CAPS + o;
      if (MODE == 2) lg += blog[bidx];
      if (MODE == 1 && dh == 0) blog[bidx] = lg;
      const float e = __expf(lg);  // no max-subtract: |lg| small
      float sm = e;
#pragma unroll
      for (int s = 2; s < 64; s <<= 1) sm += __shfl_xor(sm, s, 64);
      const float c = e / sm;
#pragma unroll
      for (int j = 0; j < 8; ++j) acc[bb][j] += c * X[j];
    }
    __syncthreads();
  }

  const size_t pbase = ((size_t)blockIdx.x * 4 + blockIdx.y) * (16 * 512);
#pragma unroll
  for (int bb = 0; bb < 4; ++bb) {
    const int bl = wv * 4 + bb;
    float4* dst =
        (float4*)(partials + pbase + (size_t)bl * 512 + o * 16 + dh * 8);
    dst[0] = make_float4(acc[bb][0], acc[bb][1], acc[bb][2], acc[bb][3]);
    dst[1] = make_float4(acc[bb][4], acc[bb][5], acc[bb][6], acc[bb][7]);
  }
}

// ---------------------------------------------------------------------------
// Reduce partials over 256 i-chunks, squash over d -> dst[b][o][d]
// ---------------------------------------------------------------------------
__global__ __launch_bounds__(256) void reduce_squash(
    const float* __restrict__ partials, float* __restrict__ dst) {
  const int t = blockIdx.x * 256 + threadIdx.x;  // (b, od)
  const int b = t >> 9;
  const int r = t & 511;
  const int bg = b >> 4, bl = b & 15;
  const size_t elem = (size_t)bl * 512 + r;
  float s = 0.f;
  for (int blk = 0; blk < NPBLK; ++blk)
    s += partials[(size_t)(blk * 4 + bg) * (16 * 512) + elem];
  float sq = s * s;
  sq += __shfl_xor(sq, 1, 64);
  sq += __shfl_xor(sq, 2, 64);
  sq += __shfl_xor(sq, 4, 64);
  sq += __shfl_xor(sq, 8, 64);
  const float sc = sq / (1.f + sq) / (sqrtf(sq) + 1e-8f);
  dst[t] = s * sc;
}

// ---------------------------------------------------------------------------
// VAE head
// ---------------------------------------------------------------------------
__global__ __launch_bounds__(256) void fc1_relu(
    const float* __restrict__ outc, const float* __restrict__ w1,
    const float* __restrict__ b1, float* __restrict__ h) {
  const int gid = blockIdx.x * 256 + threadIdx.x;
  const int n = gid >> 10, j = gid & 1023;
  float s = b1[j];
#pragma unroll
  for (int k = 0; k < 16; ++k) s += outc[n * 16 + k] * w1[k * 1024 + j];
  h[gid] = fmaxf(s, 0.f);
}

__global__ __launch_bounds__(256) void fc2_mu(
    const float* __restrict__ h, const float* __restrict__ w2,
    const float* __restrict__ b2, float* __restrict__ dout) {
  __shared__ float lh[4 * 1024];
  const int tid = threadIdx.x;
  const int nl = tid >> 6, m = tid & 63;
  const int n0 = blockIdx.x * 4;
  for (int idx = tid; idx < 4096; idx += 256)
    lh[idx] = h[(size_t)n0 * 1024 + idx];
  __syncthreads();
  float s = b2[m];
  const float* hr = lh + nl * 1024;
#pragma unroll 8
  for (int j = 0; j < 1024; ++j) s += hr[j] * w2[j * 64 + m];
  const int n = n0 + nl;
  dout[n * 64 + m] = s;
  dout[131072 + n * 64 + m] = s;
}

__global__ __launch_bounds__(256) void fc_var(
    const float* __restrict__ outc, const float* __restrict__ wv,
    const float* __restrict__ bv, float* __restrict__ dout) {
  const int gid = blockIdx.x * 256 + threadIdx.x;
  const int n = gid >> 6, m = gid & 63;
  float s = bv[m];
#pragma unroll
  for (int k = 0; k < 16; ++k) s += outc[n * 16 + k] * wv[k * 64 + m];
  const float sp = (s > 0.f) ? (s + log1pf(__expf(-s))) : log1pf(__expf(s));
  dout[262144 + gid] = sp + 1e-8f;
}

// ---------------------------------------------------------------------------
extern "C" void kernel_launch(void* const* d_in, const int* in_sizes, int n_in,
                              void* d_out, int out_size, void* d_ws,
                              size_t ws_size, hipStream_t stream) {
  const float* x = (const float*)d_in[0];
  const float* conv_w = (const float*)d_in[1];
  const float* bn_gamma = (const float*)d_in[2];
  const float* bn_beta = (const float*)d_in[3];
  const float* bn_mean = (const float*)d_in[4];
  const float* bn_var = (const float*)d_in[5];
  const float* caps_w = (const float*)d_in[6];
  const float* fcm_w1 = (const float*)d_in[7];
  const float* fcm_b1 = (const float*)d_in[8];
  const float* fcm_w2 = (const float*)d_in[9];
  const float* fcm_b2 = (const float*)d_in[10];
  const float* fcv_w = (const float*)d_in[11];
  const float* fcv_b = (const float*)d_in[12];
  float* out = (float*)d_out;
  float* ws = (float*)d_ws;

  float* pose = ws + OFF_POSE;
  float* blog = ws + OFF_BLOG;
  float* part = ws + OFF_PART;
  float* pv0 = ws + OFF_PV0;
  float* vbuf = ws + OFF_VBUF;
  float* outc = ws + OFF_OUTC;
  unsigned short* wbq = (unsigned short*)(ws + OFF_WB);
  float* bias = ws + OFF_BIAS;
  unsigned short* wr = (unsigned short*)(ws + OFF_WR);
  unsigned short* aim = (unsigned short*)(ws + OFF_AIM);
  unsigned short* posebf = (unsigned short*)(ws + OFF_PBF);
  float* h = ws + OFF_H;

  cast_bf16x8<<<8192, 256, 0, stream>>>(caps_w, wr);
  prep_wb<<<512, 256, 0, stream>>>(conv_w, bn_gamma, bn_beta, bn_mean, bn_var,
                                   wbq, bias);
  prep_aim<<<dim3(64, 16), 256, 0, stream>>>(x, aim);
  conv_gemm<<<dim3(64, 8), 256, 0, stream>>>(aim, wbq, bias, pose);
  cast_bf16x8<<<1024, 256, 0, stream>>>(pose, posebf);

  // phase 0 as GEMM
  caps_v0<<<dim3(8, 32), 256, 0, stream>>>(posebf, wr, pv0);
  reduce_v0<<<128, 256, 0, stream>>>(pv0, vbuf);

  routing_phase<1><<<dim3(NPBLK, 4), 256, 0, stream>>>(
      pose, wr, vbuf, blog, part);
  reduce_squash<<<128, 256, 0, stream>>>(part, vbuf);

  routing_phase<2><<<dim3(NPBLK, 4), 256, 0, stream>>>(
      pose, wr, vbuf, blog, part);
  reduce_squash<<<128, 256, 0, stream>>>(part, outc);

  fc1_relu<<<8192, 256, 0, stream>>>(outc, fcm_w1, fcm_b1, h);
  fc2_mu<<<512, 256, 0, stream>>>(h, fcm_w2, fcm_b2, out);
  fc_var<<<512, 256, 0, stream>>>(outc, fcv_w, fcv_b, out);
}

// Round 9
// 424.856 us; speedup vs baseline: 1.7410x; 1.0909x over previous
//
#include <hip/hip_runtime.h>
#include <cstdint>
#include <cstddef>

#define B 64
#define PCH 512
#define O_CAPS 32
#define OD 16
#define IDC 8
#define I_CAPS 4096
#define ICHUNK 16
#define NPBLK 256  // I_CAPS / ICHUNK
#define KDIM 4608  // 512*9

typedef __attribute__((ext_vector_type(8))) short bf16x8;
typedef __attribute__((ext_vector_type(4))) float f32x4;
typedef __attribute__((ext_vector_type(8))) unsigned short u16x8;
typedef _Float16 h2 __attribute__((ext_vector_type(2)));
typedef _Float16 f16x8v __attribute__((ext_vector_type(8)));

#if defined(__has_builtin)
#if __has_builtin(__builtin_amdgcn_fdot2)
#define HAVE_FDOT2 1
#endif
#endif

// workspace layout (in floats)
#define OFF_PH 0                    // pose f16: 2,097,152 ushorts
#define SZ_PH (B * I_CAPS * IDC / 2)                  // 1,048,576 floats
#define OFF_PART (OFF_PH + SZ_PH)
#define SZ_PART ((size_t)NPBLK * 4 * 16 * 512)        // 8,388,608
// aim (bf16, 9,437,184 float-equiv) occupies part + 1M spill; dead before
// caps_v0/pv0/part are written.
#define OFF_AIM OFF_PART
#define OFF_PV0 OFF_PART            // 1,048,576 floats, after aim dead
#define OFF_SPILL (OFF_PART + SZ_PART)                // aim tail
#define OFF_VBUF (OFF_SPILL + 1048576)
#define SZ_V (B * O_CAPS * OD)                        // 32,768
#define OFF_VBUF2 (OFF_VBUF + SZ_V)
#define OFF_OUTC (OFF_VBUF2 + SZ_V)
#define OFF_WB (OFF_OUTC + SZ_V)                      // bf16 512*4608
#define OFF_BIAS (OFF_WB + (PCH * KDIM) / 2)
#define OFF_WRH (OFF_BIAS + 512)                      // f16 caps_w
#define SZ_WRH ((size_t)O_CAPS * I_CAPS * OD * IDC / 2)  // 8,388,608 floats
#define OFF_H OFF_PART              // h (2M floats) after part dead

__device__ inline unsigned short f2bf(float f) {
  union { float f; unsigned int u; } v; v.f = f;
  unsigned int r = v.u + 0x7fff + ((v.u >> 16) & 1);  // RNE
  return (unsigned short)(r >> 16);
}

union HU { u16x8 v; _Float16 h[8]; h2 p[4]; };

__device__ inline unsigned short f2h(float f) {
  union { _Float16 h; unsigned short u; } c;
  c.h = (_Float16)f;  // v_cvt_f16_f32, RNE
  return c.u;
}

// ---------------------------------------------------------------------------
// cast_f16x8: fp32 -> f16 flat copy, 8 elems/thread (caps_w -> wrh).
// ---------------------------------------------------------------------------
__global__ __launch_bounds__(256) void cast_f16x8(
    const float* __restrict__ src, unsigned short* __restrict__ dst) {
  const size_t t = (size_t)blockIdx.x * 256 + threadIdx.x;
  const float4* s = (const float4*)src + t * 2;
  const float4 a = s[0], b = s[1];
  HU u;
  u.h[0] = (_Float16)a.x; u.h[1] = (_Float16)a.y;
  u.h[2] = (_Float16)a.z; u.h[3] = (_Float16)a.w;
  u.h[4] = (_Float16)b.x; u.h[5] = (_Float16)b.y;
  u.h[6] = (_Float16)b.z; u.h[7] = (_Float16)b.w;
  ((u16x8*)dst)[t] = u.v;
}

// ---------------------------------------------------------------------------
// prep_wb: Wb[n][k] = bf16(conv_w[n][k] * inv[n]); bias[n] = beta - mean*inv.
// ---------------------------------------------------------------------------
__global__ __launch_bounds__(256) void prep_wb(
    const float* __restrict__ cw, const float* __restrict__ gamma,
    const float* __restrict__ beta, const float* __restrict__ mean,
    const float* __restrict__ var, unsigned short* __restrict__ wb,
    float* __restrict__ bias) {
  const int n = blockIdx.x;
  const float inv = gamma[n] * rsqrtf(var[n] + 1e-5f);
  if (threadIdx.x == 0) bias[n] = beta[n] - mean[n] * inv;
  for (int k = threadIdx.x; k < KDIM; k += 256)
    wb[(size_t)n * KDIM + k] = f2bf(cw[(size_t)n * KDIM + k] * inv);
}

// ---------------------------------------------------------------------------
// prep_aim: im2col to bf16. Aim[m=(b,px)][k=ci*9+tap]
// ---------------------------------------------------------------------------
__global__ __launch_bounds__(256) void prep_aim(
    const float* __restrict__ x, unsigned short* __restrict__ aim) {
  __shared__ float lxp[32 * 100];
  const int b = blockIdx.x;
  const int ci0 = blockIdx.y * 32;
  const int tid = threadIdx.x;
  for (int t = tid; t < 3200; t += 256) lxp[t] = 0.f;
  __syncthreads();
  for (int t = tid; t < 2048; t += 256) {
    const int ci = t >> 6, px = t & 63;
    lxp[ci * 100 + 11 + (px >> 3) * 10 + (px & 7)] =
        x[((size_t)b * PCH + ci0 + ci) * 64 + px];
  }
  __syncthreads();
  for (int t = tid; t < 4608; t += 256) {
    const int px = t / 72;
    const int kk = (t - px * 72) * 4;
    unsigned short v[4];
#pragma unroll
    for (int j = 0; j < 4; ++j) {
      const int k = kk + j;
      const int ci = k / 9;
      const int tap = k - ci * 9;
      const int kh = tap / 3, kw = tap - kh * 3;
      v[j] = f2bf(lxp[ci * 100 + ((px >> 3) + kh) * 10 + (px & 7) + kw]);
    }
    ushort4* dst =
        (ushort4*)(aim + (size_t)(b * 64 + px) * KDIM + ci0 * 9 + kk);
    *dst = make_ushort4(v[0], v[1], v[2], v[3]);
  }
}

// ---------------------------------------------------------------------------
// conv_gemm: 64x64 tiles, mfma 16x16x32_bf16, global_load_lds staging with
// XOR swizzle, fused bias+ReLU+squash -> pose_h (f16). Grid (64 m, 8 n):
// m-sharers land on one XCD (Aim L2-resident).
// ---------------------------------------------------------------------------
__global__ __launch_bounds__(256) void conv_gemm(
    const unsigned short* __restrict__ aim, const unsigned short* __restrict__ wb,
    const float* __restrict__ bias, unsigned short* __restrict__ pose_h) {
  __shared__ unsigned short lA[64 * 64];
  __shared__ unsigned short lB[64 * 64];
  const int tid = threadIdx.x;
  const int lane = tid & 63, wv = tid >> 6;
  const int wm = wv & 1, wn = wv >> 1;
  const int m0 = blockIdx.x * 64;  // = batch * 64
  const int n0 = blockIdx.y * 64;
  const int rsub = lane >> 3, seg = lane & 7;

  f32x4 acc[2][2];
#pragma unroll
  for (int a = 0; a < 2; ++a)
#pragma unroll
    for (int c = 0; c < 2; ++c) acc[a][c] = (f32x4){0.f, 0.f, 0.f, 0.f};

  for (int k0 = 0; k0 < KDIM; k0 += 64) {
    __syncthreads();
#pragma unroll
    for (int it = 0; it < 2; ++it) {
      const int r = it * 32 + wv * 8 + rsub;
      const int c = seg ^ (r & 7);
      const unsigned short* ga = aim + (size_t)(m0 + r) * KDIM + k0 + c * 8;
      __builtin_amdgcn_global_load_lds(
          (const __attribute__((address_space(1))) void*)ga,
          (__attribute__((address_space(3))) void*)(lA + (it * 32 + wv * 8) * 64),
          16, 0, 0);
      const unsigned short* gb = wb + (size_t)(n0 + r) * KDIM + k0 + c * 8;
      __builtin_amdgcn_global_load_lds(
          (const __attribute__((address_space(1))) void*)gb,
          (__attribute__((address_space(3))) void*)(lB + (it * 32 + wv * 8) * 64),
          16, 0, 0);
    }
    __syncthreads();
#pragma unroll
    for (int kc = 0; kc < 2; ++kc) {
      const int g = kc * 4 + (lane >> 4);
      const int ml = wm * 32 + (lane & 15);
      const int nl = wn * 32 + (lane & 15);
      const int sa = (g ^ (ml & 7)) * 8;
      const int sb = (g ^ (nl & 7)) * 8;
      const bf16x8 a0 = *(const bf16x8*)(lA + (ml + 0) * 64 + sa);
      const bf16x8 a1 = *(const bf16x8*)(lA + (ml + 16) * 64 + sa);
      const bf16x8 b0 = *(const bf16x8*)(lB + (nl + 0) * 64 + sb);
      const bf16x8 b1 = *(const bf16x8*)(lB + (nl + 16) * 64 + sb);
      acc[0][0] = __builtin_amdgcn_mfma_f32_16x16x32_bf16(a0, b0, acc[0][0], 0, 0, 0);
      acc[0][1] = __builtin_amdgcn_mfma_f32_16x16x32_bf16(a0, b1, acc[0][1], 0, 0, 0);
      acc[1][0] = __builtin_amdgcn_mfma_f32_16x16x32_bf16(a1, b0, acc[1][0], 0, 0, 0);
      acc[1][1] = __builtin_amdgcn_mfma_f32_16x16x32_bf16(a1, b1, acc[1][1], 0, 0, 0);
    }
  }

  const int bq = blockIdx.x;
  float bsv[2];
#pragma unroll
  for (int ni = 0; ni < 2; ++ni)
    bsv[ni] = bias[n0 + wn * 32 + ni * 16 + (lane & 15)];
#pragma unroll
  for (int mi = 0; mi < 2; ++mi) {
#pragma unroll
    for (int ni = 0; ni < 2; ++ni) {
      const int n = n0 + wn * 32 + ni * 16 + (lane & 15);
#pragma unroll
      for (int reg = 0; reg < 4; ++reg) {
        float v = fmaxf(acc[mi][ni][reg] + bsv[ni], 0.f);
        float s2 = v * v;
        s2 += __shfl_xor(s2, 1, 64);
        s2 += __shfl_xor(s2, 2, 64);
        s2 += __shfl_xor(s2, 4, 64);
        const float sc = s2 / (1.f + s2) / (sqrtf(s2) + 1e-8f);
        const int px = wm * 32 + mi * 16 + (lane >> 4) * 4 + reg;
        pose_h[((size_t)bq * I_CAPS + (n >> 3) * 64 + px) * IDC + (n & 7)] =
            f2h(v * sc);
      }
    }
  }
}

// ---------------------------------------------------------------------------
// caps_v0: phase-0 routing as f16 MFMA GEMM (c uniform = 1/32).
// C[64 b][512 (o,d)] = pose_h[b][32768 (i,k)] . Wt^T; grid (8 n, 32 ksplit).
// ---------------------------------------------------------------------------
__global__ __launch_bounds__(256) void caps_v0(
    const unsigned short* __restrict__ pose_h,
    const unsigned short* __restrict__ wrh, float* __restrict__ pv0) {
  __shared__ unsigned short lA[64 * 64];
  __shared__ unsigned short lB[64 * 64];
  const int tid = threadIdx.x;
  const int lane = tid & 63, wv = tid >> 6;
  const int wm = wv & 1, wn = wv >> 1;
  const int o0 = blockIdx.x * 4;
  const int ks = blockIdx.y;
  const int rsub = lane >> 3, seg = lane & 7;

  f32x4 acc[2][2];
#pragma unroll
  for (int a = 0; a < 2; ++a)
#pragma unroll
    for (int c = 0; c < 2; ++c) acc[a][c] = (f32x4){0.f, 0.f, 0.f, 0.f};

  for (int kt = 0; kt < 16; ++kt) {
    const int k0 = ks * 1024 + kt * 64;
    const int i0 = k0 >> 3;
    __syncthreads();
#pragma unroll
    for (int it = 0; it < 2; ++it) {
      const int r = it * 32 + wv * 8 + rsub;
      const int c = seg ^ (r & 7);
      const unsigned short* ga = pose_h + (size_t)r * 32768 + k0 + c * 8;
      __builtin_amdgcn_global_load_lds(
          (const __attribute__((address_space(1))) void*)ga,
          (__attribute__((address_space(3))) void*)(lA + (it * 32 + wv * 8) * 64),
          16, 0, 0);
    }
#pragma unroll
    for (int h = 0; h < 2; ++h) {
      const int idx = h * 256 + tid;
      const int d = idx & 15;
      const int il = (idx >> 4) & 7;
      const int ol = idx >> 7;
      const u16x8 v = *(const u16x8*)(wrh + (size_t)(o0 + ol) * 524288 +
                                      (size_t)(i0 + il) * 128 + d * 8);
      const int np = ol * 16 + d;
      *(u16x8*)(lB + np * 64 + (il ^ (np & 7)) * 8) = v;
    }
    __syncthreads();
#pragma unroll
    for (int kc = 0; kc < 2; ++kc) {
      const int g = kc * 4 + (lane >> 4);
      const int ml = wm * 32 + (lane & 15);
      const int nl = wn * 32 + (lane & 15);
      const int sa = (g ^ (ml & 7)) * 8;
      const int sb = (g ^ (nl & 7)) * 8;
      const f16x8v a0 = *(const f16x8v*)(lA + (ml + 0) * 64 + sa);
      const f16x8v a1 = *(const f16x8v*)(lA + (ml + 16) * 64 + sa);
      const f16x8v b0 = *(const f16x8v*)(lB + (nl + 0) * 64 + sb);
      const f16x8v b1 = *(const f16x8v*)(lB + (nl + 16) * 64 + sb);
      acc[0][0] = __builtin_amdgcn_mfma_f32_16x16x32_f16(a0, b0, acc[0][0], 0, 0, 0);
      acc[0][1] = __builtin_amdgcn_mfma_f32_16x16x32_f16(a0, b1, acc[0][1], 0, 0, 0);
      acc[1][0] = __builtin_amdgcn_mfma_f32_16x16x32_f16(a1, b0, acc[1][0], 0, 0, 0);
      acc[1][1] = __builtin_amdgcn_mfma_f32_16x16x32_f16(a1, b1, acc[1][1], 0, 0, 0);
    }
  }
#pragma unroll
  for (int mi = 0; mi < 2; ++mi) {
#pragma unroll
    for (int ni = 0; ni < 2; ++ni) {
      const int n = blockIdx.x * 64 + wn * 32 + ni * 16 + (lane & 15);
#pragma unroll
      for (int reg = 0; reg < 4; ++reg) {
        const int m = wm * 32 + mi * 16 + (lane >> 4) * 4 + reg;
        pv0[(size_t)(ks * 64 + m) * 512 + n] = acc[mi][ni][reg];
      }
    }
  }
}

// ---------------------------------------------------------------------------
// reduce_v0: sum 32 k-splits, scale 1/32, squash over d -> vbuf (= v0).
// ---------------------------------------------------------------------------
__global__ __launch_bounds__(256) void reduce_v0(
    const float* __restrict__ pv0, float* __restrict__ vbuf) {
  const int t = blockIdx.x * 256 + threadIdx.x;
  const int b = t >> 9;
  const int r = t & 511;
  float s = 0.f;
#pragma unroll 8
  for (int ks = 0; ks < 32; ++ks)
    s += pv0[(size_t)(ks * 64 + b) * 512 + r];
  s *= (1.0f / 32.0f);
  float sq = s * s;
  sq += __shfl_xor(sq, 1, 64);
  sq += __shfl_xor(sq, 2, 64);
  sq += __shfl_xor(sq, 4, 64);
  sq += __shfl_xor(sq, 8, 64);
  const float sc = sq / (1.f + sq) / (sqrtf(sq) + 1e-8f);
  vbuf[t] = s * sc;
}

// ---------------------------------------------------------------------------
// Routing phase v6: no blog (logits for iter2 = (v0+v1).X — caller passes the
// summed v-vector), f16 W+pose with v_dot2_f32_f16 (fallback: scalar cvt).
// 256 thr = 4 waves x 4 b; register acc; bf16->f16 LDS staging (pitch-65);
// vrow hoisted out of the i-loop (was 128 redundant global loads/wave).
// ---------------------------------------------------------------------------
__global__ __launch_bounds__(256, 2) void routing_phase(
    const unsigned short* __restrict__ pose_h,
    const unsigned short* __restrict__ wrh,
    const float* __restrict__ vb, float* __restrict__ partials) {
  __shared__ u16x8 lw[2][8 * 65];  // 2 x 8.3 KB
  const int tid = threadIdx.x;
  const int lane = tid & 63;
  const int wv = tid >> 6;
  const int o = lane >> 1, dh = lane & 1;
  const int i0 = blockIdx.x * ICHUNK;
  const int b0 = blockIdx.y * 16;

  const int sl = tid >> 3;
  const int sq = tid & 7;
  const u16x8* wr8 = (const u16x8*)wrh;

  float acc[4][8];
  float vr[4][8];
#pragma unroll
  for (int bb = 0; bb < 4; ++bb) {
    const int b = b0 + wv * 4 + bb;
    const float4* vp =
        (const float4*)(vb + ((size_t)(b * O_CAPS + o) * OD) + dh * 8);
    const float4 v0 = vp[0], v1 = vp[1];
    vr[bb][0] = v0.x; vr[bb][1] = v0.y; vr[bb][2] = v0.z; vr[bb][3] = v0.w;
    vr[bb][4] = v1.x; vr[bb][5] = v1.y; vr[bb][6] = v1.z; vr[bb][7] = v1.w;
#pragma unroll
    for (int j = 0; j < 8; ++j) acc[bb][j] = 0.f;
  }

  auto stage = [&](int i, int buf) {
#pragma unroll
    for (int half = 0; half < 2; ++half) {
      const int l = sl + half * 32;
      lw[buf][sq * 65 + l] =
          wr8[(size_t)(l >> 1) * (I_CAPS * 16) + (size_t)i * 16 +
              (l & 1) * 8 + sq];
    }
  };

  stage(i0, 0);
  __syncthreads();

  for (int ii = 0; ii < ICHUNK; ++ii) {
    const int buf = ii & 1;
    if (ii + 1 < ICHUNK) stage(i0 + ii + 1, buf ^ 1);
    const int i = i0 + ii;
    HU w[8];
#pragma unroll
    for (int q = 0; q < 8; ++q) w[q].v = lw[buf][q * 65 + lane];
#pragma unroll
    for (int bb = 0; bb < 4; ++bb) {
      const int b = b0 + wv * 4 + bb;
      HU pk;
      pk.v = *(const u16x8*)(pose_h + ((size_t)b * I_CAPS + i) * IDC);
      float X[8];
#pragma unroll
      for (int j = 0; j < 8; ++j) {
#ifdef HAVE_FDOT2
        float s = __builtin_amdgcn_fdot2(w[j].p[3], pk.p[3], 0.f, false);
        s = __builtin_amdgcn_fdot2(w[j].p[2], pk.p[2], s, false);
        s = __builtin_amdgcn_fdot2(w[j].p[1], pk.p[1], s, false);
        X[j] = __builtin_amdgcn_fdot2(w[j].p[0], pk.p[0], s, false);
#else
        float s = 0.f;
#pragma unroll
        for (int k = 0; k < 8; ++k) s += (float)w[j].h[k] * (float)pk.h[k];
        X[j] = s;
#endif
      }
      float lg = 0.f;
#pragma unroll
      for (int j = 0; j < 8; ++j) lg += vr[bb][j] * X[j];
      lg += __shfl_xor(lg, 1, 64);  // full v.X over 16 d
      const float e = __expf(lg);   // no max-subtract: |lg| small
      float sm = e;
#pragma unroll
      for (int s = 2; s < 64; s <<= 1) sm += __shfl_xor(sm, s, 64);
      const float c = e / sm;
#pragma unroll
      for (int j = 0; j < 8; ++j) acc[bb][j] += c * X[j];
    }
    __syncthreads();
  }

  const size_t pbase = ((size_t)blockIdx.x * 4 + blockIdx.y) * (16 * 512);
#pragma unroll
  for (int bb = 0; bb < 4; ++bb) {
    const int bl = wv * 4 + bb;
    float4* dst =
        (float4*)(partials + pbase + (size_t)bl * 512 + o * 16 + dh * 8);
    dst[0] = make_float4(acc[bb][0], acc[bb][1], acc[bb][2], acc[bb][3]);
    dst[1] = make_float4(acc[bb][4], acc[bb][5], acc[bb][6], acc[bb][7]);
  }
}

// ---------------------------------------------------------------------------
// reduce_squash<ADDV>: sum 256 i-chunk partials, squash over d; if ADDV,
// add vprev (producing vsum = v0 + v1 for the final routing pass).
// ---------------------------------------------------------------------------
template <int ADDV>
__global__ __launch_bounds__(256) void reduce_squash(
    const float* __restrict__ partials, const float* __restrict__ vprev,
    float* __restrict__ dst) {
  const int t = blockIdx.x * 256 + threadIdx.x;  // (b, od)
  const int b = t >> 9;
  const int r = t & 511;
  const int bg = b >> 4, bl = b & 15;
  const size_t elem = (size_t)bl * 512 + r;
  float s = 0.f;
  for (int blk = 0; blk < NPBLK; ++blk)
    s += partials[(size_t)(blk * 4 + bg) * (16 * 512) + elem];
  float sq = s * s;
  sq += __shfl_xor(sq, 1, 64);
  sq += __shfl_xor(sq, 2, 64);
  sq += __shfl_xor(sq, 4, 64);
  sq += __shfl_xor(sq, 8, 64);
  const float sc = sq / (1.f + sq) / (sqrtf(sq) + 1e-8f);
  float val = s * sc;
  if (ADDV) val += vprev[t];
  dst[t] = val;
}

// ---------------------------------------------------------------------------
// VAE head
// ---------------------------------------------------------------------------
__global__ __launch_bounds__(256) void fc1_relu(
    const float* __restrict__ outc, const float* __restrict__ w1,
    const float* __restrict__ b1, float* __restrict__ h) {
  const int gid = blockIdx.x * 256 + threadIdx.x;
  const int n = gid >> 10, j = gid & 1023;
  float s = b1[j];
#pragma unroll
  for (int k = 0; k < 16; ++k) s += outc[n * 16 + k] * w1[k * 1024 + j];
  h[gid] = fmaxf(s, 0.f);
}

__global__ __launch_bounds__(256) void fc2_mu(
    const float* __restrict__ h, const float* __restrict__ w2,
    const float* __restrict__ b2, float* __restrict__ dout) {
  __shared__ float lh[4 * 1024];
  const int tid = threadIdx.x;
  const int nl = tid >> 6, m = tid & 63;
  const int n0 = blockIdx.x * 4;
  for (int idx = tid; idx < 4096; idx += 256)
    lh[idx] = h[(size_t)n0 * 1024 + idx];
  __syncthreads();
  float s = b2[m];
  const float* hr = lh + nl * 1024;
#pragma unroll 8
  for (int j = 0; j < 1024; ++j) s += hr[j] * w2[j * 64 + m];
  const int n = n0 + nl;
  dout[n * 64 + m] = s;
  dout[131072 + n * 64 + m] = s;
}

__global__ __launch_bounds__(256) void fc_var(
    const float* __restrict__ outc, const float* __restrict__ wv,
    const float* __restrict__ bv, float* __restrict__ dout) {
  const int gid = blockIdx.x * 256 + threadIdx.x;
  const int n = gid >> 6, m = gid & 63;
  float s = bv[m];
#pragma unroll
  for (int k = 0; k < 16; ++k) s += outc[n * 16 + k] * wv[k * 64 + m];
  const float sp = (s > 0.f) ? (s + log1pf(__expf(-s))) : log1pf(__expf(s));
  dout[262144 + gid] = sp + 1e-8f;
}

// ---------------------------------------------------------------------------
extern "C" void kernel_launch(void* const* d_in, const int* in_sizes, int n_in,
                              void* d_out, int out_size, void* d_ws,
                              size_t ws_size, hipStream_t stream) {
  const float* x = (const float*)d_in[0];
  const float* conv_w = (const float*)d_in[1];
  const float* bn_gamma = (const float*)d_in[2];
  const float* bn_beta = (const float*)d_in[3];
  const float* bn_mean = (const float*)d_in[4];
  const float* bn_var = (const float*)d_in[5];
  const float* caps_w = (const float*)d_in[6];
  const float* fcm_w1 = (const float*)d_in[7];
  const float* fcm_b1 = (const float*)d_in[8];
  const float* fcm_w2 = (const float*)d_in[9];
  const float* fcm_b2 = (const float*)d_in[10];
  const float* fcv_w = (const float*)d_in[11];
  const float* fcv_b = (const float*)d_in[12];
  float* out = (float*)d_out;
  float* ws = (float*)d_ws;

  unsigned short* pose_h = (unsigned short*)(ws + OFF_PH);
  float* part = ws + OFF_PART;
  float* pv0 = ws + OFF_PV0;
  float* vbuf = ws + OFF_VBUF;
  float* vbuf2 = ws + OFF_VBUF2;
  float* outc = ws + OFF_OUTC;
  unsigned short* wbq = (unsigned short*)(ws + OFF_WB);
  float* bias = ws + OFF_BIAS;
  unsigned short* wrh = (unsigned short*)(ws + OFF_WRH);
  unsigned short* aim = (unsigned short*)(ws + OFF_AIM);
  float* h = ws + OFF_H;

  cast_f16x8<<<8192, 256, 0, stream>>>(caps_w, wrh);
  prep_wb<<<512, 256, 0, stream>>>(conv_w, bn_gamma, bn_beta, bn_mean, bn_var,
                                   wbq, bias);
  prep_aim<<<dim3(64, 16), 256, 0, stream>>>(x, aim);
  conv_gemm<<<dim3(64, 8), 256, 0, stream>>>(aim, wbq, bias, pose_h);

  // iter 0: uniform c as f16 MFMA GEMM -> v0
  caps_v0<<<dim3(8, 32), 256, 0, stream>>>(pose_h, wrh, pv0);
  reduce_v0<<<128, 256, 0, stream>>>(pv0, vbuf);

  // iter 1: logits = v0.X
  routing_phase<<<dim3(NPBLK, 4), 256, 0, stream>>>(pose_h, wrh, vbuf, part);
  reduce_squash<1><<<128, 256, 0, stream>>>(part, vbuf, vbuf2);  // vsum = v0+v1

  // iter 2: logits = (v0+v1).X
  routing_phase<<<dim3(NPBLK, 4), 256, 0, stream>>>(pose_h, wrh, vbuf2, part);
  reduce_squash<0><<<128, 256, 0, stream>>>(part, nullptr, outc);

  fc1_relu<<<8192, 256, 0, stream>>>(outc, fcm_w1, fcm_b1, h);
  fc2_mu<<<512, 256, 0, stream>>>(h, fcm_w2, fcm_b2, out);
  fc_var<<<512, 256, 0, stream>>>(outc, fcv_w, fcv_b, out);
}